// Round 1
// baseline (791.481 us; speedup 1.0000x reference)
//
#include <hip/hip_runtime.h>
#include <math.h>

#define B_ROWS     32768
#define STATE_DIM  64
#define ACTION_DIM 16
#define HIDDEN     512
#define ENSEMBLE   7
#define TOP_K      5
#define IN_DIM     80    // STATE_DIM + ACTION_DIM
#define OUT_DIM    130   // 2*(STATE_DIM+1)
#define D_OUT      65    // STATE_DIM+1

#define BM         16
#define THREADS    256
#define TILES_PER_E ((B_ROWS + BM - 1) / BM)   // 2048

// ---------------- bucket rows by ensemble index ----------------
__global__ void bucket_kernel(const int* __restrict__ idx,
                              int* __restrict__ cnt,
                              int* __restrict__ bucket) {
    int b = blockIdx.x * blockDim.x + threadIdx.x;
    if (b >= B_ROWS) return;
    int e = idx[b];
    e = min(max(e, 0), ENSEMBLE - 1);   // memory safety
    int pos = atomicAdd(&cnt[e], 1);
    bucket[e * B_ROWS + pos] = b;
}

// ---------------- fused 3-layer MLP + epilogue ----------------
__launch_bounds__(THREADS, 2)
__global__ void mlp_kernel(const float* __restrict__ state,
                           const float* __restrict__ action,
                           const float* __restrict__ eps,
                           const float* __restrict__ W1, const float* __restrict__ b1,
                           const float* __restrict__ W2, const float* __restrict__ b2,
                           const float* __restrict__ W3, const float* __restrict__ b3,
                           const int* __restrict__ cnt, const int* __restrict__ bucket,
                           float* __restrict__ out) {
    __shared__ float xs[BM][IN_DIM];     // 16x80   = 5120 B
    __shared__ float h1[BM][HIDDEN];     // 16x512  = 32768 B
    __shared__ float h2[BM][HIDDEN];     // 16x512  = 32768 B
    __shared__ float os[BM][OUT_DIM];    // 16x130  = 8320 B
    __shared__ int   rows[BM];

    const int e    = blockIdx.x / TILES_PER_E;
    const int tile = blockIdx.x % TILES_PER_E;
    const int n    = cnt[e];
    const int m0   = tile * BM;
    if (m0 >= n) return;
    const int nrows = min(BM, n - m0);
    const int t = threadIdx.x;

    if (t < BM) {
        rows[t] = (t < nrows) ? bucket[e * B_ROWS + m0 + t]
                              : bucket[e * B_ROWS + m0];
    }
    __syncthreads();

    // ---- stage x = concat(state, action): 16 x 80 ----
    for (int i = t; i < BM * IN_DIM; i += THREADS) {
        int r = i / IN_DIM, c = i % IN_DIM;
        int rb = rows[r];
        xs[r][c] = (c < STATE_DIM) ? state[(size_t)rb * STATE_DIM + c]
                                   : action[(size_t)rb * ACTION_DIM + (c - STATE_DIM)];
    }
    __syncthreads();

    const int c0 = 2 * t;   // this thread owns output cols c0, c0+1 (0..511)

    // ---- layer 1: h1 = relu(x @ W1[e] + b1[e]) ----
    {
        const float* We = W1 + (size_t)e * IN_DIM * HIDDEN;
        float acc0[BM], acc1[BM];
        const float bias0 = b1[(size_t)e * HIDDEN + c0];
        const float bias1 = b1[(size_t)e * HIDDEN + c0 + 1];
        #pragma unroll
        for (int r = 0; r < BM; ++r) { acc0[r] = bias0; acc1[r] = bias1; }
        for (int k = 0; k < IN_DIM; k += 4) {
            float2 w0 = *(const float2*)&We[(size_t)(k + 0) * HIDDEN + c0];
            float2 w1 = *(const float2*)&We[(size_t)(k + 1) * HIDDEN + c0];
            float2 w2 = *(const float2*)&We[(size_t)(k + 2) * HIDDEN + c0];
            float2 w3 = *(const float2*)&We[(size_t)(k + 3) * HIDDEN + c0];
            #pragma unroll
            for (int r = 0; r < BM; ++r) {
                float4 x = *(const float4*)&xs[r][k];
                acc0[r] = fmaf(x.x, w0.x, acc0[r]); acc1[r] = fmaf(x.x, w0.y, acc1[r]);
                acc0[r] = fmaf(x.y, w1.x, acc0[r]); acc1[r] = fmaf(x.y, w1.y, acc1[r]);
                acc0[r] = fmaf(x.z, w2.x, acc0[r]); acc1[r] = fmaf(x.z, w2.y, acc1[r]);
                acc0[r] = fmaf(x.w, w3.x, acc0[r]); acc1[r] = fmaf(x.w, w3.y, acc1[r]);
            }
        }
        #pragma unroll
        for (int r = 0; r < BM; ++r) {
            float2 hv = make_float2(fmaxf(acc0[r], 0.f), fmaxf(acc1[r], 0.f));
            *(float2*)&h1[r][c0] = hv;
        }
    }
    __syncthreads();

    // ---- layer 2: h2 = relu(h1 @ W2[e] + b2[e]) ----
    {
        const float* We = W2 + (size_t)e * HIDDEN * HIDDEN;
        float acc0[BM], acc1[BM];
        const float bias0 = b2[(size_t)e * HIDDEN + c0];
        const float bias1 = b2[(size_t)e * HIDDEN + c0 + 1];
        #pragma unroll
        for (int r = 0; r < BM; ++r) { acc0[r] = bias0; acc1[r] = bias1; }
        for (int k = 0; k < HIDDEN; k += 4) {
            float2 w0 = *(const float2*)&We[(size_t)(k + 0) * HIDDEN + c0];
            float2 w1 = *(const float2*)&We[(size_t)(k + 1) * HIDDEN + c0];
            float2 w2 = *(const float2*)&We[(size_t)(k + 2) * HIDDEN + c0];
            float2 w3 = *(const float2*)&We[(size_t)(k + 3) * HIDDEN + c0];
            #pragma unroll
            for (int r = 0; r < BM; ++r) {
                float4 x = *(const float4*)&h1[r][k];
                acc0[r] = fmaf(x.x, w0.x, acc0[r]); acc1[r] = fmaf(x.x, w0.y, acc1[r]);
                acc0[r] = fmaf(x.y, w1.x, acc0[r]); acc1[r] = fmaf(x.y, w1.y, acc1[r]);
                acc0[r] = fmaf(x.z, w2.x, acc0[r]); acc1[r] = fmaf(x.z, w2.y, acc1[r]);
                acc0[r] = fmaf(x.w, w3.x, acc0[r]); acc1[r] = fmaf(x.w, w3.y, acc1[r]);
            }
        }
        #pragma unroll
        for (int r = 0; r < BM; ++r) {
            float2 hv = make_float2(fmaxf(acc0[r], 0.f), fmaxf(acc1[r], 0.f));
            *(float2*)&h2[r][c0] = hv;
        }
    }
    __syncthreads();

    // ---- layer 3: o = h2 @ W3[e] + b3[e]  (BM x 130) ----
    {
        const float* We = W3 + (size_t)e * HIDDEN * OUT_DIM;
        for (int i = t; i < BM * OUT_DIM; i += THREADS) {
            int r = i / OUT_DIM, c = i % OUT_DIM;
            float acc = b3[(size_t)e * OUT_DIM + c];
            for (int k = 0; k < HIDDEN; k += 4) {
                float4 h = *(const float4*)&h2[r][k];
                acc = fmaf(h.x, We[(size_t)(k + 0) * OUT_DIM + c], acc);
                acc = fmaf(h.y, We[(size_t)(k + 1) * OUT_DIM + c], acc);
                acc = fmaf(h.z, We[(size_t)(k + 2) * OUT_DIM + c], acc);
                acc = fmaf(h.w, We[(size_t)(k + 3) * OUT_DIM + c], acc);
            }
            os[r][c] = acc;
        }
    }
    __syncthreads();

    // ---- epilogue: mu/log_std/eps + select + residual ----
    for (int i = t; i < BM * D_OUT; i += THREADS) {
        int r = i / D_OUT, c = i % D_OUT;
        if (r >= nrows) continue;
        int rb = rows[r];
        float mu = os[r][c];
        float ls = fminf(fmaxf(os[r][c + D_OUT], -20.f), 2.f);
        float y  = fmaf(expf(ls), eps[(size_t)rb * D_OUT + c], mu);
        if (c < STATE_DIM) {
            out[(size_t)rb * STATE_DIM + c] = state[(size_t)rb * STATE_DIM + c] + y;
        } else {
            out[(size_t)B_ROWS * STATE_DIM + rb] = y;
        }
    }
}

extern "C" void kernel_launch(void* const* d_in, const int* in_sizes, int n_in,
                              void* d_out, int out_size, void* d_ws, size_t ws_size,
                              hipStream_t stream) {
    const float* state  = (const float*)d_in[0];
    const float* action = (const float*)d_in[1];
    const float* eps    = (const float*)d_in[2];
    const float* W1     = (const float*)d_in[3];
    const float* b1     = (const float*)d_in[4];
    const float* W2     = (const float*)d_in[5];
    const float* b2     = (const float*)d_in[6];
    const float* W3     = (const float*)d_in[7];
    const float* b3     = (const float*)d_in[8];
    const int*   idx    = (const int*)d_in[9];
    float* out = (float*)d_out;

    int* cnt    = (int*)d_ws;                       // ENSEMBLE counters
    int* bucket = (int*)((char*)d_ws + 256);        // ENSEMBLE * B row ids

    hipMemsetAsync(cnt, 0, ENSEMBLE * sizeof(int), stream);
    bucket_kernel<<<(B_ROWS + 255) / 256, 256, 0, stream>>>(idx, cnt, bucket);
    mlp_kernel<<<TOP_K * TILES_PER_E, THREADS, 0, stream>>>(
        state, action, eps, W1, b1, W2, b2, W3, b3, cnt, bucket, out);
}

// Round 2
// 333.822 us; speedup vs baseline: 2.3710x; 2.3710x over previous
//
#include <hip/hip_runtime.h>
#include <math.h>

#define B_ROWS     32768
#define STATE_DIM  64
#define ACTION_DIM 16
#define HIDDEN     512
#define ENSEMBLE   7
#define TOP_K      5
#define IN_DIM     80    // STATE_DIM + ACTION_DIM
#define OUT_DIM    130   // 2*(STATE_DIM+1)
#define D_OUT      65    // STATE_DIM+1

// ---- MFMA kernel geometry ----
#define BM         32
#define MTHREADS   512                           // 8 waves
#define TILES_PER_E ((B_ROWS + BM - 1) / BM)     // 1024

// ---- packed weight dims (K padded to mult of 32, N padded to mult of 16) ----
#define L1_K8 12      // K=96 (real 80)
#define L2_K8 64      // K=512
#define L3_K8 64      // K=512
#define L3_N  144     // N=130 padded to 9 col-tiles

#define N_W1 (TOP_K * L1_K8 * HIDDEN * 8)
#define N_W2 (TOP_K * L2_K8 * HIDDEN * 8)
#define N_W3 (TOP_K * L3_K8 * L3_N * 8)

#define OFF_CNT    0
#define OFF_BUCKET 256
#define OFF_W1HI   (OFF_BUCKET + ENSEMBLE * B_ROWS * 4)
#define OFF_W1LO   (OFF_W1HI + N_W1 * 2)
#define OFF_W2HI   (OFF_W1LO + N_W1 * 2)
#define OFF_W2LO   (OFF_W2HI + N_W2 * 2)
#define OFF_W3HI   (OFF_W2LO + N_W2 * 2)
#define OFF_W3LO   (OFF_W3HI + N_W3 * 2)
#define WS_NEEDED  ((size_t)(OFF_W3LO + N_W3 * 2))

typedef __attribute__((ext_vector_type(8))) short short8;
typedef __attribute__((ext_vector_type(4))) float f32x4;

__device__ __forceinline__ unsigned short f2bf(float x) {
    unsigned int u = __float_as_uint(x);
    u = (u + 0x7FFFu + ((u >> 16) & 1u)) >> 16;
    return (unsigned short)u;
}
__device__ __forceinline__ float bf2f(unsigned short h) {
    return __uint_as_float(((unsigned int)h) << 16);
}

// ---------------- bucket rows by ensemble index ----------------
__global__ void bucket_kernel(const int* __restrict__ idx,
                              int* __restrict__ cnt,
                              int* __restrict__ bucket) {
    int b = blockIdx.x * blockDim.x + threadIdx.x;
    if (b >= B_ROWS) return;
    int e = idx[b];
    e = min(max(e, 0), TOP_K - 1);
    int pos = atomicAdd(&cnt[e], 1);
    bucket[e * B_ROWS + pos] = b;
}

// ---------------- pack weights fp32 -> (bf16 hi, bf16 lo) MFMA layout ----------------
// layout: [e][k8][n][8] so a B-fragment (8 consecutive k of one column) is 16B contiguous
__global__ void pack_kernel(const float* __restrict__ W1, const float* __restrict__ W2,
                            const float* __restrict__ W3,
                            unsigned short* __restrict__ w1hi, unsigned short* __restrict__ w1lo,
                            unsigned short* __restrict__ w2hi, unsigned short* __restrict__ w2lo,
                            unsigned short* __restrict__ w3hi, unsigned short* __restrict__ w3lo) {
    const int G1 = L1_K8 * HIDDEN;   // 6144
    const int G2 = L2_K8 * HIDDEN;   // 32768
    const int G3 = L3_K8 * L3_N;     // 9216
    const int GPE = G1 + G2 + G3;    // 48128
    int g = blockIdx.x * blockDim.x + threadIdx.x;
    if (g >= TOP_K * GPE) return;
    int e = g / GPE, r = g % GPE;

    const float* src; unsigned short *dhi, *dlo;
    size_t dst; int k8, n, Kreal, Nreal, srcN;
    if (r < G1) {
        k8 = r / HIDDEN; n = r % HIDDEN;
        src = W1 + (size_t)e * IN_DIM * HIDDEN; Kreal = IN_DIM; Nreal = HIDDEN; srcN = HIDDEN;
        dhi = w1hi; dlo = w1lo; dst = (((size_t)e * L1_K8 + k8) * HIDDEN + n) * 8;
    } else if (r < G1 + G2) {
        int rr = r - G1; k8 = rr / HIDDEN; n = rr % HIDDEN;
        src = W2 + (size_t)e * HIDDEN * HIDDEN; Kreal = HIDDEN; Nreal = HIDDEN; srcN = HIDDEN;
        dhi = w2hi; dlo = w2lo; dst = (((size_t)e * L2_K8 + k8) * HIDDEN + n) * 8;
    } else {
        int rr = r - G1 - G2; k8 = rr / L3_N; n = rr % L3_N;
        src = W3 + (size_t)e * HIDDEN * OUT_DIM; Kreal = HIDDEN; Nreal = OUT_DIM; srcN = OUT_DIM;
        dhi = w3hi; dlo = w3lo; dst = (((size_t)e * L3_K8 + k8) * L3_N + n) * 8;
    }
    short8 hi, lo;
    #pragma unroll
    for (int j = 0; j < 8; ++j) {
        int k = k8 * 8 + j;
        float v = (k < Kreal && n < Nreal) ? src[(size_t)k * srcN + n] : 0.f;
        unsigned short h = f2bf(v);
        hi[j] = (short)h;
        lo[j] = (short)f2bf(v - bf2f(h));
    }
    *(short8*)(dhi + dst) = hi;
    *(short8*)(dlo + dst) = lo;
}

// ---------------- one GEMM layer (N=512, relu, split output to LDS) ----------------
// A in LDS (hi/lo, XOR-swizzled, row stride kd_bytes); B packed in global; 8 waves,
// wave wv owns cols [64*wv, 64*wv+64) for both 16-row tiles.
__device__ __forceinline__ void gemm_layer(const char* Ahi, const char* Alo,
                                           int kd_bytes, int ksteps,
                                           const unsigned short* __restrict__ Bhi,
                                           const unsigned short* __restrict__ Blo,
                                           const float* __restrict__ bias,
                                           char* Ohi, char* Olo,
                                           int lane, int wv) {
    const int lc = lane & 15;       // col within tile / A row within tile
    const int kg = lane >> 4;       // k-group 0..3
    const int col0 = wv * 64;
    f32x4 acc[2][4];
    #pragma unroll
    for (int ctl = 0; ctl < 4; ++ctl) {
        float b = bias[col0 + ctl * 16 + lc];
        acc[0][ctl] = (f32x4){b, b, b, b};
        acc[1][ctl] = acc[0][ctl];
    }
    #pragma unroll 2
    for (int ks = 0; ks < ksteps; ++ks) {
        short8 ah[2], al[2];
        #pragma unroll
        for (int rt = 0; rt < 2; ++rt) {
            int row = rt * 16 + lc;
            int lin = row * kd_bytes + (ks * 32 + kg * 8) * 2;
            int ad = lin ^ ((row & 7) << 4);
            ah[rt] = *(const short8*)(Ahi + ad);
            al[rt] = *(const short8*)(Alo + ad);
        }
        short8 bh[4], bl[4];
        #pragma unroll
        for (int ctl = 0; ctl < 4; ++ctl) {
            size_t boff = ((size_t)(ks * 4 + kg) * HIDDEN + (col0 + ctl * 16 + lc)) * 8;
            bh[ctl] = *(const short8*)(Bhi + boff);
            bl[ctl] = *(const short8*)(Blo + boff);
        }
        #pragma unroll
        for (int ctl = 0; ctl < 4; ++ctl)
        #pragma unroll
        for (int rt = 0; rt < 2; ++rt) {
            acc[rt][ctl] = __builtin_amdgcn_mfma_f32_16x16x32_bf16(ah[rt], bh[ctl], acc[rt][ctl], 0, 0, 0);
            acc[rt][ctl] = __builtin_amdgcn_mfma_f32_16x16x32_bf16(ah[rt], bl[ctl], acc[rt][ctl], 0, 0, 0);
            acc[rt][ctl] = __builtin_amdgcn_mfma_f32_16x16x32_bf16(al[rt], bh[ctl], acc[rt][ctl], 0, 0, 0);
        }
    }
    // relu + hi/lo split + swizzled store (output row stride 1024B = [32][512] bf16)
    #pragma unroll
    for (int rt = 0; rt < 2; ++rt)
    #pragma unroll
    for (int ctl = 0; ctl < 4; ++ctl)
    #pragma unroll
    for (int q = 0; q < 4; ++q) {
        int row = rt * 16 + kg * 4 + q;          // C layout: row=(lane>>4)*4+q
        int col = col0 + ctl * 16 + lc;          // C layout: col=lane&15
        float v = fmaxf(acc[rt][ctl][q], 0.f);
        unsigned short h = f2bf(v);
        unsigned short l = f2bf(v - bf2f(h));
        int lin = row * 1024 + col * 2;
        int ad = lin ^ ((row & 7) << 4);
        *(unsigned short*)(Ohi + ad) = h;
        *(unsigned short*)(Olo + ad) = l;
    }
}

// ---------------- fused MLP, split-bf16 MFMA ----------------
__launch_bounds__(MTHREADS, 1)
__global__ void mlp_mfma_kernel(const float* __restrict__ state,
                                const float* __restrict__ action,
                                const float* __restrict__ eps,
                                const float* __restrict__ b1,
                                const float* __restrict__ b2,
                                const float* __restrict__ b3,
                                const unsigned short* __restrict__ w1hi, const unsigned short* __restrict__ w1lo,
                                const unsigned short* __restrict__ w2hi, const unsigned short* __restrict__ w2lo,
                                const unsigned short* __restrict__ w3hi, const unsigned short* __restrict__ w3lo,
                                const int* __restrict__ cnt, const int* __restrict__ bucket,
                                float* __restrict__ out) {
    __shared__ char smem[131072];
    __shared__ int rows[BM];
    char* h1hi = smem;                 // [32][512] bf16 swizzled (32 KB)
    char* h1lo = smem + 32768;
    char* h2hi = smem + 65536;
    char* h2lo = smem + 98304;
    char* xhi  = smem + 65536;         // [32][128] bf16 swizzled (8 KB, aliases h2hi)
    char* xlo  = smem + 65536 + 8192;  // (aliases h2hi)
    float* os  = (float*)smem;         // [32][132] fp32 (16.9 KB, aliases h1)

    const int e    = blockIdx.x / TILES_PER_E;
    const int tile = blockIdx.x % TILES_PER_E;
    const int n    = cnt[e];
    const int m0   = tile * BM;
    if (m0 >= n) return;
    const int nrows = min(BM, n - m0);
    const int t = threadIdx.x;
    const int lane = t & 63;
    const int wv = t >> 6;

    if (t < BM) rows[t] = (t < nrows) ? bucket[e * B_ROWS + m0 + t]
                                      : bucket[e * B_ROWS + m0];
    __syncthreads();

    // ---- stage x = concat(state, action) hi/lo, 32x128 (cols>=80 zero), swizzled ----
    for (int i = t; i < BM * 128; i += MTHREADS) {
        int r = i >> 7, c = i & 127;
        int rb = rows[r];
        float v = 0.f;
        if (c < STATE_DIM)      v = state[(size_t)rb * STATE_DIM + c];
        else if (c < IN_DIM)    v = action[(size_t)rb * ACTION_DIM + (c - STATE_DIM)];
        unsigned short h = f2bf(v);
        unsigned short l = f2bf(v - bf2f(h));
        int lin = r * 256 + c * 2;
        int ad = lin ^ ((r & 7) << 4);
        *(unsigned short*)(xhi + ad) = h;
        *(unsigned short*)(xlo + ad) = l;
    }
    __syncthreads();

    // ---- layer 1: h1 = relu(x @ W1 + b1), K=96(padded), N=512 ----
    gemm_layer(xhi, xlo, 256, 3,
               w1hi + (size_t)e * L1_K8 * HIDDEN * 8, w1lo + (size_t)e * L1_K8 * HIDDEN * 8,
               b1 + (size_t)e * HIDDEN, h1hi, h1lo, lane, wv);
    __syncthreads();

    // ---- layer 2: h2 = relu(h1 @ W2 + b2), K=512, N=512 ----
    gemm_layer(h1hi, h1lo, 1024, 16,
               w2hi + (size_t)e * L2_K8 * HIDDEN * 8, w2lo + (size_t)e * L2_K8 * HIDDEN * 8,
               b2 + (size_t)e * HIDDEN, h2hi, h2lo, lane, wv);
    __syncthreads();

    // ---- layer 3: o = h2 @ W3 + b3, K=512, N=144(padded), fp32 out to LDS ----
    {
        const unsigned short* Bhi = w3hi + (size_t)e * L3_K8 * L3_N * 8;
        const unsigned short* Blo = w3lo + (size_t)e * L3_K8 * L3_N * 8;
        const float* bias = b3 + (size_t)e * OUT_DIM;
        const int lc = lane & 15, kg = lane >> 4;
        for (int ct = wv; ct < 9; ct += 8) {
            f32x4 acc[2];
            acc[0] = (f32x4){0.f, 0.f, 0.f, 0.f};
            acc[1] = acc[0];
            #pragma unroll 2
            for (int ks = 0; ks < 16; ++ks) {
                short8 ah[2], al[2];
                #pragma unroll
                for (int rt = 0; rt < 2; ++rt) {
                    int row = rt * 16 + lc;
                    int lin = row * 1024 + (ks * 32 + kg * 8) * 2;
                    int ad = lin ^ ((row & 7) << 4);
                    ah[rt] = *(const short8*)(h2hi + ad);
                    al[rt] = *(const short8*)(h2lo + ad);
                }
                size_t boff = ((size_t)(ks * 4 + kg) * L3_N + (ct * 16 + lc)) * 8;
                short8 bh = *(const short8*)(Bhi + boff);
                short8 bl = *(const short8*)(Blo + boff);
                #pragma unroll
                for (int rt = 0; rt < 2; ++rt) {
                    acc[rt] = __builtin_amdgcn_mfma_f32_16x16x32_bf16(ah[rt], bh, acc[rt], 0, 0, 0);
                    acc[rt] = __builtin_amdgcn_mfma_f32_16x16x32_bf16(ah[rt], bl, acc[rt], 0, 0, 0);
                    acc[rt] = __builtin_amdgcn_mfma_f32_16x16x32_bf16(al[rt], bh, acc[rt], 0, 0, 0);
                }
            }
            #pragma unroll
            for (int rt = 0; rt < 2; ++rt)
            #pragma unroll
            for (int q = 0; q < 4; ++q) {
                int row = rt * 16 + kg * 4 + q;
                int col = ct * 16 + lc;
                if (col < OUT_DIM) os[row * 132 + col] = acc[rt][q] + bias[col];
            }
        }
    }
    __syncthreads();

    // ---- epilogue ----
    for (int i = t; i < BM * D_OUT; i += MTHREADS) {
        int r = i / D_OUT, c = i % D_OUT;
        if (r >= nrows) continue;
        int rb = rows[r];
        float mu = os[r * 132 + c];
        float ls = fminf(fmaxf(os[r * 132 + c + D_OUT], -20.f), 2.f);
        float y  = fmaf(expf(ls), eps[(size_t)rb * D_OUT + c], mu);
        if (c < STATE_DIM) {
            out[(size_t)rb * STATE_DIM + c] = state[(size_t)rb * STATE_DIM + c] + y;
        } else {
            out[(size_t)B_ROWS * STATE_DIM + rb] = y;
        }
    }
}

// ================= fallback fp32 path (round-1 kernel, used if ws too small) =================
#define FB_BM      16
#define FB_THREADS 256
#define FB_TILES   ((B_ROWS + FB_BM - 1) / FB_BM)

__launch_bounds__(FB_THREADS, 2)
__global__ void mlp_fp32_kernel(const float* __restrict__ state,
                                const float* __restrict__ action,
                                const float* __restrict__ eps,
                                const float* __restrict__ W1, const float* __restrict__ b1,
                                const float* __restrict__ W2, const float* __restrict__ b2,
                                const float* __restrict__ W3, const float* __restrict__ b3,
                                const int* __restrict__ cnt, const int* __restrict__ bucket,
                                float* __restrict__ out) {
    __shared__ float xs[FB_BM][IN_DIM];
    __shared__ float h1[FB_BM][HIDDEN];
    __shared__ float h2[FB_BM][HIDDEN];
    __shared__ float os[FB_BM][OUT_DIM];
    __shared__ int   rows[FB_BM];

    const int e    = blockIdx.x / FB_TILES;
    const int tile = blockIdx.x % FB_TILES;
    const int n    = cnt[e];
    const int m0   = tile * FB_BM;
    if (m0 >= n) return;
    const int nrows = min(FB_BM, n - m0);
    const int t = threadIdx.x;

    if (t < FB_BM) rows[t] = (t < nrows) ? bucket[e * B_ROWS + m0 + t] : bucket[e * B_ROWS + m0];
    __syncthreads();

    for (int i = t; i < FB_BM * IN_DIM; i += FB_THREADS) {
        int r = i / IN_DIM, c = i % IN_DIM;
        int rb = rows[r];
        xs[r][c] = (c < STATE_DIM) ? state[(size_t)rb * STATE_DIM + c]
                                   : action[(size_t)rb * ACTION_DIM + (c - STATE_DIM)];
    }
    __syncthreads();

    const int c0 = 2 * t;
    {
        const float* We = W1 + (size_t)e * IN_DIM * HIDDEN;
        float acc0[FB_BM], acc1[FB_BM];
        const float bias0 = b1[(size_t)e * HIDDEN + c0];
        const float bias1 = b1[(size_t)e * HIDDEN + c0 + 1];
        #pragma unroll
        for (int r = 0; r < FB_BM; ++r) { acc0[r] = bias0; acc1[r] = bias1; }
        for (int k = 0; k < IN_DIM; k += 4) {
            float2 w0 = *(const float2*)&We[(size_t)(k + 0) * HIDDEN + c0];
            float2 w1 = *(const float2*)&We[(size_t)(k + 1) * HIDDEN + c0];
            float2 w2 = *(const float2*)&We[(size_t)(k + 2) * HIDDEN + c0];
            float2 w3 = *(const float2*)&We[(size_t)(k + 3) * HIDDEN + c0];
            #pragma unroll
            for (int r = 0; r < FB_BM; ++r) {
                float4 x = *(const float4*)&xs[r][k];
                acc0[r] = fmaf(x.x, w0.x, acc0[r]); acc1[r] = fmaf(x.x, w0.y, acc1[r]);
                acc0[r] = fmaf(x.y, w1.x, acc0[r]); acc1[r] = fmaf(x.y, w1.y, acc1[r]);
                acc0[r] = fmaf(x.z, w2.x, acc0[r]); acc1[r] = fmaf(x.z, w2.y, acc1[r]);
                acc0[r] = fmaf(x.w, w3.x, acc0[r]); acc1[r] = fmaf(x.w, w3.y, acc1[r]);
            }
        }
        #pragma unroll
        for (int r = 0; r < FB_BM; ++r)
            *(float2*)&h1[r][c0] = make_float2(fmaxf(acc0[r], 0.f), fmaxf(acc1[r], 0.f));
    }
    __syncthreads();
    {
        const float* We = W2 + (size_t)e * HIDDEN * HIDDEN;
        float acc0[FB_BM], acc1[FB_BM];
        const float bias0 = b2[(size_t)e * HIDDEN + c0];
        const float bias1 = b2[(size_t)e * HIDDEN + c0 + 1];
        #pragma unroll
        for (int r = 0; r < FB_BM; ++r) { acc0[r] = bias0; acc1[r] = bias1; }
        for (int k = 0; k < HIDDEN; k += 4) {
            float2 w0 = *(const float2*)&We[(size_t)(k + 0) * HIDDEN + c0];
            float2 w1 = *(const float2*)&We[(size_t)(k + 1) * HIDDEN + c0];
            float2 w2 = *(const float2*)&We[(size_t)(k + 2) * HIDDEN + c0];
            float2 w3 = *(const float2*)&We[(size_t)(k + 3) * HIDDEN + c0];
            #pragma unroll
            for (int r = 0; r < FB_BM; ++r) {
                float4 x = *(const float4*)&h1[r][k];
                acc0[r] = fmaf(x.x, w0.x, acc0[r]); acc1[r] = fmaf(x.x, w0.y, acc1[r]);
                acc0[r] = fmaf(x.y, w1.x, acc0[r]); acc1[r] = fmaf(x.y, w1.y, acc1[r]);
                acc0[r] = fmaf(x.z, w2.x, acc0[r]); acc1[r] = fmaf(x.z, w2.y, acc1[r]);
                acc0[r] = fmaf(x.w, w3.x, acc0[r]); acc1[r] = fmaf(x.w, w3.y, acc1[r]);
            }
        }
        #pragma unroll
        for (int r = 0; r < FB_BM; ++r)
            *(float2*)&h2[r][c0] = make_float2(fmaxf(acc0[r], 0.f), fmaxf(acc1[r], 0.f));
    }
    __syncthreads();
    {
        const float* We = W3 + (size_t)e * HIDDEN * OUT_DIM;
        for (int i = t; i < FB_BM * OUT_DIM; i += FB_THREADS) {
            int r = i / OUT_DIM, c = i % OUT_DIM;
            float acc = b3[(size_t)e * OUT_DIM + c];
            for (int k = 0; k < HIDDEN; k += 4) {
                float4 h = *(const float4*)&h2[r][k];
                acc = fmaf(h.x, We[(size_t)(k + 0) * OUT_DIM + c], acc);
                acc = fmaf(h.y, We[(size_t)(k + 1) * OUT_DIM + c], acc);
                acc = fmaf(h.z, We[(size_t)(k + 2) * OUT_DIM + c], acc);
                acc = fmaf(h.w, We[(size_t)(k + 3) * OUT_DIM + c], acc);
            }
            os[r][c] = acc;
        }
    }
    __syncthreads();
    for (int i = t; i < FB_BM * D_OUT; i += FB_THREADS) {
        int r = i / D_OUT, c = i % D_OUT;
        if (r >= nrows) continue;
        int rb = rows[r];
        float mu = os[r][c];
        float ls = fminf(fmaxf(os[r][c + D_OUT], -20.f), 2.f);
        float y  = fmaf(expf(ls), eps[(size_t)rb * D_OUT + c], mu);
        if (c < STATE_DIM) out[(size_t)rb * STATE_DIM + c] = state[(size_t)rb * STATE_DIM + c] + y;
        else               out[(size_t)B_ROWS * STATE_DIM + rb] = y;
    }
}

extern "C" void kernel_launch(void* const* d_in, const int* in_sizes, int n_in,
                              void* d_out, int out_size, void* d_ws, size_t ws_size,
                              hipStream_t stream) {
    const float* state  = (const float*)d_in[0];
    const float* action = (const float*)d_in[1];
    const float* eps    = (const float*)d_in[2];
    const float* W1     = (const float*)d_in[3];
    const float* b1     = (const float*)d_in[4];
    const float* W2     = (const float*)d_in[5];
    const float* b2     = (const float*)d_in[6];
    const float* W3     = (const float*)d_in[7];
    const float* b3     = (const float*)d_in[8];
    const int*   idx    = (const int*)d_in[9];
    float* out = (float*)d_out;

    int* cnt    = (int*)((char*)d_ws + OFF_CNT);
    int* bucket = (int*)((char*)d_ws + OFF_BUCKET);

    hipMemsetAsync(cnt, 0, ENSEMBLE * sizeof(int), stream);
    bucket_kernel<<<(B_ROWS + 255) / 256, 256, 0, stream>>>(idx, cnt, bucket);

    if (ws_size >= WS_NEEDED) {
        unsigned short* w1hi = (unsigned short*)((char*)d_ws + OFF_W1HI);
        unsigned short* w1lo = (unsigned short*)((char*)d_ws + OFF_W1LO);
        unsigned short* w2hi = (unsigned short*)((char*)d_ws + OFF_W2HI);
        unsigned short* w2lo = (unsigned short*)((char*)d_ws + OFF_W2LO);
        unsigned short* w3hi = (unsigned short*)((char*)d_ws + OFF_W3HI);
        unsigned short* w3lo = (unsigned short*)((char*)d_ws + OFF_W3LO);

        const int groups = TOP_K * (L1_K8 * HIDDEN + L2_K8 * HIDDEN + L3_K8 * L3_N);
        pack_kernel<<<(groups + 255) / 256, 256, 0, stream>>>(
            W1, W2, W3, w1hi, w1lo, w2hi, w2lo, w3hi, w3lo);

        mlp_mfma_kernel<<<TOP_K * TILES_PER_E, MTHREADS, 0, stream>>>(
            state, action, eps, b1, b2, b3,
            w1hi, w1lo, w2hi, w2lo, w3hi, w3lo, cnt, bucket, out);
    } else {
        mlp_fp32_kernel<<<TOP_K * FB_TILES, FB_THREADS, 0, stream>>>(
            state, action, eps, W1, b1, W2, b2, W3, b3, cnt, bucket, out);
    }
}

// Round 3
// 236.738 us; speedup vs baseline: 3.3433x; 1.4101x over previous
//
#include <hip/hip_runtime.h>
#include <math.h>

#define B_ROWS     32768
#define STATE_DIM  64
#define ACTION_DIM 16
#define HIDDEN     512
#define ENSEMBLE   7
#define TOP_K      5
#define IN_DIM     80    // STATE_DIM + ACTION_DIM
#define OUT_DIM    130   // 2*(STATE_DIM+1)
#define D_OUT      65    // STATE_DIM+1

// ---- MFMA kernel geometry ----
#define BM         64
#define MTHREADS   1024                          // 16 waves
#define TILES_PER_E ((B_ROWS + BM - 1) / BM)     // 512

// ---- packed weight dims ----
#define L1_K8 12      // K=96 (real 80)
#define L2_K8 64      // K=512
#define L3_K8 64      // K=512
#define L3_N  144     // N=130 padded to 9 col-tiles

#define N_W1 (TOP_K * L1_K8 * HIDDEN * 8)
#define N_W2 (TOP_K * L2_K8 * HIDDEN * 8)
#define N_W3 (TOP_K * L3_K8 * L3_N * 8)

#define OFF_CNT    0
#define OFF_BUCKET 256
#define OFF_W1HI   (OFF_BUCKET + ENSEMBLE * B_ROWS * 4)
#define OFF_W1LO   (OFF_W1HI + N_W1 * 2)
#define OFF_W2HI   (OFF_W1LO + N_W1 * 2)
#define OFF_W2LO   (OFF_W2HI + N_W2 * 2)
#define OFF_W3HI   (OFF_W2LO + N_W2 * 2)
#define OFF_W3LO   (OFF_W3HI + N_W3 * 2)
#define WS_NEEDED  ((size_t)(OFF_W3LO + N_W3 * 2))

typedef __attribute__((ext_vector_type(8))) short short8;
typedef __attribute__((ext_vector_type(4))) float f32x4;

__device__ __forceinline__ unsigned short f2bf(float x) {
    unsigned int u = __float_as_uint(x);
    u = (u + 0x7FFFu + ((u >> 16) & 1u)) >> 16;
    return (unsigned short)u;
}
__device__ __forceinline__ float bf2f(unsigned short h) {
    return __uint_as_float(((unsigned int)h) << 16);
}

// ---------------- bucket rows by ensemble index (wave-aggregated atomics) ----------------
__global__ void bucket_kernel(const int* __restrict__ idx,
                              int* __restrict__ cnt,
                              int* __restrict__ bucket) {
    int b = blockIdx.x * blockDim.x + threadIdx.x;
    int lane = threadIdx.x & 63;
    int e = -1;
    if (b < B_ROWS) e = min(max(idx[b], 0), TOP_K - 1);
    #pragma unroll
    for (int ev = 0; ev < TOP_K; ++ev) {
        unsigned long long m = __ballot(e == ev);
        if (m == 0ull) continue;
        int leader = __ffsll((unsigned long long)m) - 1;
        int base = 0;
        if (lane == leader) base = atomicAdd(&cnt[ev], __popcll(m));
        base = __shfl(base, leader);
        if (e == ev) {
            int rank = __popcll(m & ((1ull << lane) - 1ull));
            bucket[ev * B_ROWS + base + rank] = b;
        }
    }
}

// ---------------- pack weights fp32 -> (bf16 hi, bf16 lo) MFMA layout ----------------
// layout: [e][k8][n][8] so a B-fragment (8 consecutive k of one column) is 16B contiguous
__global__ void pack_kernel(const float* __restrict__ W1, const float* __restrict__ W2,
                            const float* __restrict__ W3,
                            unsigned short* __restrict__ w1hi, unsigned short* __restrict__ w1lo,
                            unsigned short* __restrict__ w2hi, unsigned short* __restrict__ w2lo,
                            unsigned short* __restrict__ w3hi, unsigned short* __restrict__ w3lo) {
    const int G1 = L1_K8 * HIDDEN;   // 6144
    const int G2 = L2_K8 * HIDDEN;   // 32768
    const int G3 = L3_K8 * L3_N;     // 9216
    const int GPE = G1 + G2 + G3;    // 48128
    int g = blockIdx.x * blockDim.x + threadIdx.x;
    if (g >= TOP_K * GPE) return;
    int e = g / GPE, r = g % GPE;

    const float* src; unsigned short *dhi, *dlo;
    size_t dst; int k8, n, Kreal, Nreal, srcN;
    if (r < G1) {
        k8 = r / HIDDEN; n = r % HIDDEN;
        src = W1 + (size_t)e * IN_DIM * HIDDEN; Kreal = IN_DIM; Nreal = HIDDEN; srcN = HIDDEN;
        dhi = w1hi; dlo = w1lo; dst = (((size_t)e * L1_K8 + k8) * HIDDEN + n) * 8;
    } else if (r < G1 + G2) {
        int rr = r - G1; k8 = rr / HIDDEN; n = rr % HIDDEN;
        src = W2 + (size_t)e * HIDDEN * HIDDEN; Kreal = HIDDEN; Nreal = HIDDEN; srcN = HIDDEN;
        dhi = w2hi; dlo = w2lo; dst = (((size_t)e * L2_K8 + k8) * HIDDEN + n) * 8;
    } else {
        int rr = r - G1 - G2; k8 = rr / L3_N; n = rr % L3_N;
        src = W3 + (size_t)e * HIDDEN * OUT_DIM; Kreal = HIDDEN; Nreal = OUT_DIM; srcN = OUT_DIM;
        dhi = w3hi; dlo = w3lo; dst = (((size_t)e * L3_K8 + k8) * L3_N + n) * 8;
    }
    short8 hi, lo;
    #pragma unroll
    for (int j = 0; j < 8; ++j) {
        int k = k8 * 8 + j;
        float v = (k < Kreal && n < Nreal) ? src[(size_t)k * srcN + n] : 0.f;
        unsigned short h = f2bf(v);
        hi[j] = (short)h;
        lo[j] = (short)f2bf(v - bf2f(h));
    }
    *(short8*)(dhi + dst) = hi;
    *(short8*)(dlo + dst) = lo;
}

// ---------------- GEMM compute: 64 rows x 32 cols per wave, acc stays in regs ----------------
// A in LDS (hi/lo planes, row stride ASTR bytes, optional XOR swizzle);
// B packed [k8][Bn][8] in global; B double-buffered (prefetch ks+1 before MFMAs of ks).
template<int ASTR, bool SWZ>
__device__ __forceinline__ void gemm_compute(
    const char* Ahi, const char* Alo, int ksteps,
    const unsigned short* __restrict__ Bhi, const unsigned short* __restrict__ Blo,
    int Bn, const float* __restrict__ bias,
    f32x4 (&acc)[4][2], int lane, int col0)
{
    const int lc = lane & 15, kg = lane >> 4;
    #pragma unroll
    for (int ctl = 0; ctl < 2; ++ctl) {
        float b = bias[col0 + ctl * 16 + lc];
        #pragma unroll
        for (int rt = 0; rt < 4; ++rt) acc[rt][ctl] = (f32x4){b, b, b, b};
    }
    const size_t bstep = (size_t)4 * Bn * 8;   // elements per k-step
    const unsigned short* bh_p = Bhi + ((size_t)kg * Bn + col0 + lc) * 8;
    const unsigned short* bl_p = Blo + ((size_t)kg * Bn + col0 + lc) * 8;

    short8 bch0, bch1, bcl0, bcl1, bnh0, bnh1, bnl0, bnl1;
    bch0 = *(const short8*)(bh_p);       bch1 = *(const short8*)(bh_p + 128);
    bcl0 = *(const short8*)(bl_p);       bcl1 = *(const short8*)(bl_p + 128);

    for (int ks = 0; ks < ksteps; ++ks) {
        if (ks + 1 < ksteps) {
            const unsigned short* ph = bh_p + (size_t)(ks + 1) * bstep;
            const unsigned short* pl = bl_p + (size_t)(ks + 1) * bstep;
            bnh0 = *(const short8*)(ph); bnh1 = *(const short8*)(ph + 128);
            bnl0 = *(const short8*)(pl); bnl1 = *(const short8*)(pl + 128);
        }
        #pragma unroll
        for (int rt = 0; rt < 4; ++rt) {
            int row = rt * 16 + lc;
            int lin = row * ASTR + ks * 64 + kg * 16;
            if (SWZ) lin ^= (row & 7) << 4;
            short8 ah = *(const short8*)(Ahi + lin);
            short8 al = *(const short8*)(Alo + lin);
            acc[rt][0] = __builtin_amdgcn_mfma_f32_16x16x32_bf16(ah, bch0, acc[rt][0], 0, 0, 0);
            acc[rt][0] = __builtin_amdgcn_mfma_f32_16x16x32_bf16(ah, bcl0, acc[rt][0], 0, 0, 0);
            acc[rt][0] = __builtin_amdgcn_mfma_f32_16x16x32_bf16(al, bch0, acc[rt][0], 0, 0, 0);
            acc[rt][1] = __builtin_amdgcn_mfma_f32_16x16x32_bf16(ah, bch1, acc[rt][1], 0, 0, 0);
            acc[rt][1] = __builtin_amdgcn_mfma_f32_16x16x32_bf16(ah, bcl1, acc[rt][1], 0, 0, 0);
            acc[rt][1] = __builtin_amdgcn_mfma_f32_16x16x32_bf16(al, bch1, acc[rt][1], 0, 0, 0);
        }
        bch0 = bnh0; bch1 = bnh1; bcl0 = bnl0; bcl1 = bnl1;
    }
}

// relu + hi/lo split + swizzled store into h region ([64][512] bf16, stride 1024B)
__device__ __forceinline__ void store_h(char* Ohi, char* Olo,
                                        f32x4 (&acc)[4][2], int lane, int col0) {
    const int lc = lane & 15, kg = lane >> 4;
    #pragma unroll
    for (int rt = 0; rt < 4; ++rt)
    #pragma unroll
    for (int ctl = 0; ctl < 2; ++ctl)
    #pragma unroll
    for (int q = 0; q < 4; ++q) {
        int row = rt * 16 + kg * 4 + q;          // C layout: row=(lane>>4)*4+q
        int col = col0 + ctl * 16 + lc;          // C layout: col=lane&15
        float v = fmaxf(acc[rt][ctl][q], 0.f);
        unsigned short h = f2bf(v);
        unsigned short l = f2bf(v - bf2f(h));
        int lin = (row * 1024 + col * 2) ^ ((row & 7) << 4);
        *(unsigned short*)(Ohi + lin) = h;
        *(unsigned short*)(Olo + lin) = l;
    }
}

// layer-3 unit: one 16x16 col-tile (ct) x one 16-row tile (rt), K=512
__device__ __forceinline__ void l3_unit(const char* Hhi, const char* Hlo,
                                        const unsigned short* __restrict__ Bhi,
                                        const unsigned short* __restrict__ Blo,
                                        int u, int lane, f32x4& o)
{
    const int lc = lane & 15, kg = lane >> 4;
    const int ct = u >> 2, rt = u & 3;
    o = (f32x4){0.f, 0.f, 0.f, 0.f};
    const unsigned short* bh_p = Bhi + ((size_t)kg * L3_N + ct * 16 + lc) * 8;
    const unsigned short* bl_p = Blo + ((size_t)kg * L3_N + ct * 16 + lc) * 8;
    const size_t bstep = (size_t)4 * L3_N * 8;
    for (int ks = 0; ks < 16; ++ks) {
        int row = rt * 16 + lc;
        int lin = (row * 1024 + ks * 64 + kg * 16) ^ ((row & 7) << 4);
        short8 ah = *(const short8*)(Hhi + lin);
        short8 al = *(const short8*)(Hlo + lin);
        short8 bh = *(const short8*)(bh_p + (size_t)ks * bstep);
        short8 bl = *(const short8*)(bl_p + (size_t)ks * bstep);
        o = __builtin_amdgcn_mfma_f32_16x16x32_bf16(ah, bh, o, 0, 0, 0);
        o = __builtin_amdgcn_mfma_f32_16x16x32_bf16(ah, bl, o, 0, 0, 0);
        o = __builtin_amdgcn_mfma_f32_16x16x32_bf16(al, bh, o, 0, 0, 0);
    }
}

__device__ __forceinline__ void l3_store(float* os, const float* __restrict__ bias,
                                         int u, int lane, const f32x4& o) {
    const int lc = lane & 15, kg = lane >> 4;
    const int ct = u >> 2, rt = u & 3;
    int col = ct * 16 + lc;
    if (col < OUT_DIM) {
        #pragma unroll
        for (int q = 0; q < 4; ++q) {
            int row = rt * 16 + kg * 4 + q;
            os[row * 132 + col] = o[q] + bias[col];
        }
    }
}

// ---------------- fused MLP, split-bf16 MFMA, BM=64, 16 waves ----------------
__launch_bounds__(MTHREADS, 4)
__global__ void mlp_mfma_kernel(const float* __restrict__ state,
                                const float* __restrict__ action,
                                const float* __restrict__ eps,
                                const float* __restrict__ b1,
                                const float* __restrict__ b2,
                                const float* __restrict__ b3,
                                const unsigned short* __restrict__ w1hi, const unsigned short* __restrict__ w1lo,
                                const unsigned short* __restrict__ w2hi, const unsigned short* __restrict__ w2lo,
                                const unsigned short* __restrict__ w3hi, const unsigned short* __restrict__ w3lo,
                                const int* __restrict__ cnt, const int* __restrict__ bucket,
                                float* __restrict__ out) {
    __shared__ char smem[159744];
    char* xhi = smem;                    // [64][112] bf16, stride 224B (14336 B)
    char* xlo = smem + 14336;            // (14336 B)
    char* hhi = smem + 28672;            // [64][512] bf16 swizzled (65536 B) — h1 then h2
    char* hlo = smem + 94208;            // (65536 B)
    float* os = (float*)(smem + 28672);  // [64][132] fp32 (33792 B), overlays h after layer 3

    const int e    = blockIdx.x / TILES_PER_E;
    const int tile = blockIdx.x % TILES_PER_E;
    const int n    = cnt[e];
    const int m0   = tile * BM;
    if (m0 >= n) return;
    const int nrows = min(BM, n - m0);
    const int t = threadIdx.x;
    const int lane = t & 63;
    const int wv = t >> 6;
    const int col0 = wv * 32;
    const int* brow = bucket + (size_t)e * B_ROWS;

    // ---- stage x = concat(state, action) hi/lo, 64x112 (cols>=80 zero), unswizzled ----
    for (int i = t; i < BM * 112; i += MTHREADS) {
        int r = i / 112, c = i % 112;
        int rb = brow[min(m0 + r, n - 1)];
        float v = 0.f;
        if (c < STATE_DIM)      v = state[(size_t)rb * STATE_DIM + c];
        else if (c < IN_DIM)    v = action[(size_t)rb * ACTION_DIM + (c - STATE_DIM)];
        unsigned short h = f2bf(v);
        unsigned short l = f2bf(v - bf2f(h));
        *(unsigned short*)(xhi + r * 224 + c * 2) = h;
        *(unsigned short*)(xlo + r * 224 + c * 2) = l;
    }
    __syncthreads();

    f32x4 acc[4][2];

    // ---- layer 1: h1 = relu(x @ W1 + b1), K=96, N=512 ----
    gemm_compute<224, false>(xhi, xlo, 3,
        w1hi + (size_t)e * L1_K8 * HIDDEN * 8, w1lo + (size_t)e * L1_K8 * HIDDEN * 8,
        HIDDEN, b1 + (size_t)e * HIDDEN, acc, lane, col0);
    store_h(hhi, hlo, acc, lane, col0);     // h region disjoint from x: no WAR hazard
    __syncthreads();

    // ---- layer 2: h2 = relu(h1 @ W2 + b2), K=512, N=512; h2 held in regs until barrier ----
    gemm_compute<1024, true>(hhi, hlo, 16,
        w2hi + (size_t)e * L2_K8 * HIDDEN * 8, w2lo + (size_t)e * L2_K8 * HIDDEN * 8,
        HIDDEN, b2 + (size_t)e * HIDDEN, acc, lane, col0);
    __syncthreads();                        // all h1 reads complete
    store_h(hhi, hlo, acc, lane, col0);     // overwrite h1 with h2
    __syncthreads();

    // ---- layer 3: o = h2 @ W3 + b3, K=512, N=144 (36 units over 16 waves) ----
    {
        const unsigned short* Bh = w3hi + (size_t)e * L3_K8 * L3_N * 8;
        const unsigned short* Bl = w3lo + (size_t)e * L3_K8 * L3_N * 8;
        const float* b3e = b3 + (size_t)e * OUT_DIM;
        f32x4 o0, o1, o2;
        l3_unit(hhi, hlo, Bh, Bl, wv, lane, o0);
        l3_unit(hhi, hlo, Bh, Bl, wv + 16, lane, o1);
        if (wv < 4) l3_unit(hhi, hlo, Bh, Bl, wv + 32, lane, o2);
        __syncthreads();                    // all h2 reads complete
        l3_store(os, b3e, wv, lane, o0);
        l3_store(os, b3e, wv + 16, lane, o1);
        if (wv < 4) l3_store(os, b3e, wv + 32, lane, o2);
    }
    __syncthreads();

    // ---- epilogue ----
    for (int i = t; i < BM * D_OUT; i += MTHREADS) {
        int r = i / D_OUT, c = i % D_OUT;
        if (r >= nrows) continue;
        int rb = brow[m0 + r];
        float mu = os[r * 132 + c];
        float ls = fminf(fmaxf(os[r * 132 + c + D_OUT], -20.f), 2.f);
        float y  = fmaf(expf(ls), eps[(size_t)rb * D_OUT + c], mu);
        if (c < STATE_DIM) {
            out[(size_t)rb * STATE_DIM + c] = state[(size_t)rb * STATE_DIM + c] + y;
        } else {
            out[(size_t)B_ROWS * STATE_DIM + rb] = y;
        }
    }
}

// ================= fallback fp32 path (used if ws too small) =================
#define FB_BM      16
#define FB_THREADS 256
#define FB_TILES   ((B_ROWS + FB_BM - 1) / FB_BM)

__launch_bounds__(FB_THREADS, 2)
__global__ void mlp_fp32_kernel(const float* __restrict__ state,
                                const float* __restrict__ action,
                                const float* __restrict__ eps,
                                const float* __restrict__ W1, const float* __restrict__ b1,
                                const float* __restrict__ W2, const float* __restrict__ b2,
                                const float* __restrict__ W3, const float* __restrict__ b3,
                                const int* __restrict__ cnt, const int* __restrict__ bucket,
                                float* __restrict__ out) {
    __shared__ float xs[FB_BM][IN_DIM];
    __shared__ float h1[FB_BM][HIDDEN];
    __shared__ float h2[FB_BM][HIDDEN];
    __shared__ float os[FB_BM][OUT_DIM];
    __shared__ int   rows[FB_BM];

    const int e    = blockIdx.x / FB_TILES;
    const int tile = blockIdx.x % FB_TILES;
    const int n    = cnt[e];
    const int m0   = tile * FB_BM;
    if (m0 >= n) return;
    const int nrows = min(FB_BM, n - m0);
    const int t = threadIdx.x;

    if (t < FB_BM) rows[t] = (t < nrows) ? bucket[e * B_ROWS + m0 + t] : bucket[e * B_ROWS + m0];
    __syncthreads();

    for (int i = t; i < FB_BM * IN_DIM; i += FB_THREADS) {
        int r = i / IN_DIM, c = i % IN_DIM;
        int rb = rows[r];
        xs[r][c] = (c < STATE_DIM) ? state[(size_t)rb * STATE_DIM + c]
                                   : action[(size_t)rb * ACTION_DIM + (c - STATE_DIM)];
    }
    __syncthreads();

    const int c0 = 2 * t;
    {
        const float* We = W1 + (size_t)e * IN_DIM * HIDDEN;
        float acc0[FB_BM], acc1[FB_BM];
        const float bias0 = b1[(size_t)e * HIDDEN + c0];
        const float bias1 = b1[(size_t)e * HIDDEN + c0 + 1];
        #pragma unroll
        for (int r = 0; r < FB_BM; ++r) { acc0[r] = bias0; acc1[r] = bias1; }
        for (int k = 0; k < IN_DIM; k += 4) {
            float2 w0 = *(const float2*)&We[(size_t)(k + 0) * HIDDEN + c0];
            float2 w1 = *(const float2*)&We[(size_t)(k + 1) * HIDDEN + c0];
            float2 w2 = *(const float2*)&We[(size_t)(k + 2) * HIDDEN + c0];
            float2 w3 = *(const float2*)&We[(size_t)(k + 3) * HIDDEN + c0];
            #pragma unroll
            for (int r = 0; r < FB_BM; ++r) {
                float4 x = *(const float4*)&xs[r][k];
                acc0[r] = fmaf(x.x, w0.x, acc0[r]); acc1[r] = fmaf(x.x, w0.y, acc1[r]);
                acc0[r] = fmaf(x.y, w1.x, acc0[r]); acc1[r] = fmaf(x.y, w1.y, acc1[r]);
                acc0[r] = fmaf(x.z, w2.x, acc0[r]); acc1[r] = fmaf(x.z, w2.y, acc1[r]);
                acc0[r] = fmaf(x.w, w3.x, acc0[r]); acc1[r] = fmaf(x.w, w3.y, acc1[r]);
            }
        }
        #pragma unroll
        for (int r = 0; r < FB_BM; ++r)
            *(float2*)&h1[r][c0] = make_float2(fmaxf(acc0[r], 0.f), fmaxf(acc1[r], 0.f));
    }
    __syncthreads();
    {
        const float* We = W2 + (size_t)e * HIDDEN * HIDDEN;
        float acc0[FB_BM], acc1[FB_BM];
        const float bias0 = b2[(size_t)e * HIDDEN + c0];
        const float bias1 = b2[(size_t)e * HIDDEN + c0 + 1];
        #pragma unroll
        for (int r = 0; r < FB_BM; ++r) { acc0[r] = bias0; acc1[r] = bias1; }
        for (int k = 0; k < HIDDEN; k += 4) {
            float2 w0 = *(const float2*)&We[(size_t)(k + 0) * HIDDEN + c0];
            float2 w1 = *(const float2*)&We[(size_t)(k + 1) * HIDDEN + c0];
            float2 w2 = *(const float2*)&We[(size_t)(k + 2) * HIDDEN + c0];
            float2 w3 = *(const float2*)&We[(size_t)(k + 3) * HIDDEN + c0];
            #pragma unroll
            for (int r = 0; r < FB_BM; ++r) {
                float4 x = *(const float4*)&h1[r][k];
                acc0[r] = fmaf(x.x, w0.x, acc0[r]); acc1[r] = fmaf(x.x, w0.y, acc1[r]);
                acc0[r] = fmaf(x.y, w1.x, acc0[r]); acc1[r] = fmaf(x.y, w1.y, acc1[r]);
                acc0[r] = fmaf(x.z, w2.x, acc0[r]); acc1[r] = fmaf(x.z, w2.y, acc1[r]);
                acc0[r] = fmaf(x.w, w3.x, acc0[r]); acc1[r] = fmaf(x.w, w3.y, acc1[r]);
            }
        }
        #pragma unroll
        for (int r = 0; r < FB_BM; ++r)
            *(float2*)&h2[r][c0] = make_float2(fmaxf(acc0[r], 0.f), fmaxf(acc1[r], 0.f));
    }
    __syncthreads();
    {
        const float* We = W3 + (size_t)e * HIDDEN * OUT_DIM;
        for (int i = t; i < FB_BM * OUT_DIM; i += FB_THREADS) {
            int r = i / OUT_DIM, c = i % OUT_DIM;
            float acc = b3[(size_t)e * OUT_DIM + c];
            for (int k = 0; k < HIDDEN; k += 4) {
                float4 h = *(const float4*)&h2[r][k];
                acc = fmaf(h.x, We[(size_t)(k + 0) * OUT_DIM + c], acc);
                acc = fmaf(h.y, We[(size_t)(k + 1) * OUT_DIM + c], acc);
                acc = fmaf(h.z, We[(size_t)(k + 2) * OUT_DIM + c], acc);
                acc = fmaf(h.w, We[(size_t)(k + 3) * OUT_DIM + c], acc);
            }
            os[r][c] = acc;
        }
    }
    __syncthreads();
    for (int i = t; i < FB_BM * D_OUT; i += FB_THREADS) {
        int r = i / D_OUT, c = i % D_OUT;
        if (r >= nrows) continue;
        int rb = rows[r];
        float mu = os[r][c];
        float ls = fminf(fmaxf(os[r][c + D_OUT], -20.f), 2.f);
        float y  = fmaf(expf(ls), eps[(size_t)rb * D_OUT + c], mu);
        if (c < STATE_DIM) out[(size_t)rb * STATE_DIM + c] = state[(size_t)rb * STATE_DIM + c] + y;
        else               out[(size_t)B_ROWS * STATE_DIM + rb] = y;
    }
}

extern "C" void kernel_launch(void* const* d_in, const int* in_sizes, int n_in,
                              void* d_out, int out_size, void* d_ws, size_t ws_size,
                              hipStream_t stream) {
    const float* state  = (const float*)d_in[0];
    const float* action = (const float*)d_in[1];
    const float* eps    = (const float*)d_in[2];
    const float* W1     = (const float*)d_in[3];
    const float* b1     = (const float*)d_in[4];
    const float* W2     = (const float*)d_in[5];
    const float* b2     = (const float*)d_in[6];
    const float* W3     = (const float*)d_in[7];
    const float* b3     = (const float*)d_in[8];
    const int*   idx    = (const int*)d_in[9];
    float* out = (float*)d_out;

    int* cnt    = (int*)((char*)d_ws + OFF_CNT);
    int* bucket = (int*)((char*)d_ws + OFF_BUCKET);

    hipMemsetAsync(cnt, 0, ENSEMBLE * sizeof(int), stream);
    bucket_kernel<<<(B_ROWS + 255) / 256, 256, 0, stream>>>(idx, cnt, bucket);

    if (ws_size >= WS_NEEDED) {
        unsigned short* w1hi = (unsigned short*)((char*)d_ws + OFF_W1HI);
        unsigned short* w1lo = (unsigned short*)((char*)d_ws + OFF_W1LO);
        unsigned short* w2hi = (unsigned short*)((char*)d_ws + OFF_W2HI);
        unsigned short* w2lo = (unsigned short*)((char*)d_ws + OFF_W2LO);
        unsigned short* w3hi = (unsigned short*)((char*)d_ws + OFF_W3HI);
        unsigned short* w3lo = (unsigned short*)((char*)d_ws + OFF_W3LO);

        const int groups = TOP_K * (L1_K8 * HIDDEN + L2_K8 * HIDDEN + L3_K8 * L3_N);
        pack_kernel<<<(groups + 255) / 256, 256, 0, stream>>>(
            W1, W2, W3, w1hi, w1lo, w2hi, w2lo, w3hi, w3lo);

        mlp_mfma_kernel<<<TOP_K * TILES_PER_E, MTHREADS, 0, stream>>>(
            state, action, eps, b1, b2, b3,
            w1hi, w1lo, w2hi, w2lo, w3hi, w3lo, cnt, bucket, out);
    } else {
        mlp_fp32_kernel<<<TOP_K * FB_TILES, FB_THREADS, 0, stream>>>(
            state, action, eps, W1, b1, W2, b2, W3, b3, cnt, bucket, out);
    }
}

// Round 4
// 183.644 us; speedup vs baseline: 4.3099x; 1.2891x over previous
//
#include <hip/hip_runtime.h>
#include <math.h>

#define B_ROWS     32768
#define STATE_DIM  64
#define ACTION_DIM 16
#define HIDDEN     512
#define ENSEMBLE   7
#define TOP_K      5
#define IN_DIM     80    // STATE_DIM + ACTION_DIM
#define OUT_DIM    130   // 2*(STATE_DIM+1)
#define D_OUT      65    // STATE_DIM+1

// ---- MFMA kernel geometry ----
#define BM         64
#define MTHREADS   1024                          // 16 waves = 2 row-groups x 8 col-groups
#define TILES_PER_E ((B_ROWS + BM - 1) / BM)     // 512

// ---- packed weight dims ----
#define L1_K8 12      // K=96 (real 80)
#define L2_K8 64      // K=512
#define L3_K8 64      // K=512
#define L3_N  144     // N=130 padded to 9 col-tiles

#define N_W1 (TOP_K * L1_K8 * HIDDEN * 8)
#define N_W2 (TOP_K * L2_K8 * HIDDEN * 8)
#define N_W3 (TOP_K * L3_K8 * L3_N * 8)

#define OFF_CNT    0
#define OFF_BUCKET 256
#define OFF_W1HI   (OFF_BUCKET + ENSEMBLE * B_ROWS * 4)
#define OFF_W1LO   (OFF_W1HI + N_W1 * 2)
#define OFF_W2HI   (OFF_W1LO + N_W1 * 2)
#define OFF_W2LO   (OFF_W2HI + N_W2 * 2)
#define OFF_W3HI   (OFF_W2LO + N_W2 * 2)
#define OFF_W3LO   (OFF_W3HI + N_W3 * 2)
#define WS_NEEDED  ((size_t)(OFF_W3LO + N_W3 * 2))

typedef __attribute__((ext_vector_type(8))) short short8;
typedef __attribute__((ext_vector_type(4))) float f32x4;

__device__ __forceinline__ unsigned short f2bf(float x) {
    unsigned int u = __float_as_uint(x);
    u = (u + 0x7FFFu + ((u >> 16) & 1u)) >> 16;
    return (unsigned short)u;
}
__device__ __forceinline__ float bf2f(unsigned short h) {
    return __uint_as_float(((unsigned int)h) << 16);
}

// ---------------- bucket rows by ensemble index (wave-aggregated atomics) ----------------
__global__ void bucket_kernel(const int* __restrict__ idx,
                              int* __restrict__ cnt,
                              int* __restrict__ bucket) {
    int b = blockIdx.x * blockDim.x + threadIdx.x;
    int lane = threadIdx.x & 63;
    int e = -1;
    if (b < B_ROWS) e = min(max(idx[b], 0), TOP_K - 1);
    #pragma unroll
    for (int ev = 0; ev < TOP_K; ++ev) {
        unsigned long long m = __ballot(e == ev);
        if (m == 0ull) continue;
        int leader = __ffsll((unsigned long long)m) - 1;
        int base = 0;
        if (lane == leader) base = atomicAdd(&cnt[ev], __popcll(m));
        base = __shfl(base, leader);
        if (e == ev) {
            int rank = __popcll(m & ((1ull << lane) - 1ull));
            bucket[ev * B_ROWS + base + rank] = b;
        }
    }
}

// ---------------- pack weights fp32 -> (bf16 hi, bf16 lo) MFMA layout ----------------
// layout: [e][k8][n][8] so a B-fragment (8 consecutive k of one column) is 16B contiguous
__global__ void pack_kernel(const float* __restrict__ W1, const float* __restrict__ W2,
                            const float* __restrict__ W3,
                            unsigned short* __restrict__ w1hi, unsigned short* __restrict__ w1lo,
                            unsigned short* __restrict__ w2hi, unsigned short* __restrict__ w2lo,
                            unsigned short* __restrict__ w3hi, unsigned short* __restrict__ w3lo) {
    const int G1 = L1_K8 * HIDDEN;   // 6144
    const int G2 = L2_K8 * HIDDEN;   // 32768
    const int G3 = L3_K8 * L3_N;     // 9216
    const int GPE = G1 + G2 + G3;    // 48128
    int g = blockIdx.x * blockDim.x + threadIdx.x;
    if (g >= TOP_K * GPE) return;
    int e = g / GPE, r = g % GPE;

    const float* src; unsigned short *dhi, *dlo;
    size_t dst; int k8, n, Kreal, Nreal, srcN;
    if (r < G1) {
        k8 = r / HIDDEN; n = r % HIDDEN;
        src = W1 + (size_t)e * IN_DIM * HIDDEN; Kreal = IN_DIM; Nreal = HIDDEN; srcN = HIDDEN;
        dhi = w1hi; dlo = w1lo; dst = (((size_t)e * L1_K8 + k8) * HIDDEN + n) * 8;
    } else if (r < G1 + G2) {
        int rr = r - G1; k8 = rr / HIDDEN; n = rr % HIDDEN;
        src = W2 + (size_t)e * HIDDEN * HIDDEN; Kreal = HIDDEN; Nreal = HIDDEN; srcN = HIDDEN;
        dhi = w2hi; dlo = w2lo; dst = (((size_t)e * L2_K8 + k8) * HIDDEN + n) * 8;
    } else {
        int rr = r - G1 - G2; k8 = rr / L3_N; n = rr % L3_N;
        src = W3 + (size_t)e * HIDDEN * OUT_DIM; Kreal = HIDDEN; Nreal = OUT_DIM; srcN = OUT_DIM;
        dhi = w3hi; dlo = w3lo; dst = (((size_t)e * L3_K8 + k8) * L3_N + n) * 8;
    }
    short8 hi, lo;
    #pragma unroll
    for (int j = 0; j < 8; ++j) {
        int k = k8 * 8 + j;
        float v = (k < Kreal && n < Nreal) ? src[(size_t)k * srcN + n] : 0.f;
        unsigned short h = f2bf(v);
        hi[j] = (short)h;
        lo[j] = (short)f2bf(v - bf2f(h));
    }
    *(short8*)(dhi + dst) = hi;
    *(short8*)(dlo + dst) = lo;
}

// ---------------- GEMM compute: 32 rows x 64 cols per wave, acc stays in regs ----------------
// A in LDS (hi/lo planes, row stride ASTR bytes, optional XOR swizzle);
// B packed [k8][Bn][8] in global (hi/lo).
template<int ASTR, bool SWZ>
__device__ __forceinline__ void gemm_compute(
    const char* Ahi, const char* Alo, int row0, int ksteps,
    const unsigned short* __restrict__ Bhi, const unsigned short* __restrict__ Blo,
    int Bn, const float* __restrict__ bias,
    f32x4 (&acc)[2][4], int lane, int col0)
{
    const int lc = lane & 15, kg = lane >> 4;
    #pragma unroll
    for (int ctl = 0; ctl < 4; ++ctl) {
        float b = bias[col0 + ctl * 16 + lc];
        #pragma unroll
        for (int rt = 0; rt < 2; ++rt) acc[rt][ctl] = (f32x4){b, b, b, b};
    }
    const size_t bstep = (size_t)4 * Bn * 8;   // elements per k-step
    const unsigned short* bh_p = Bhi + ((size_t)kg * Bn + col0 + lc) * 8;
    const unsigned short* bl_p = Blo + ((size_t)kg * Bn + col0 + lc) * 8;

    #pragma unroll 2
    for (int ks = 0; ks < ksteps; ++ks) {
        // B loads first (long-latency, independent)
        short8 bh[4], bl[4];
        #pragma unroll
        for (int ctl = 0; ctl < 4; ++ctl) {
            bh[ctl] = *(const short8*)(bh_p + (size_t)ks * bstep + ctl * 128);
            bl[ctl] = *(const short8*)(bl_p + (size_t)ks * bstep + ctl * 128);
        }
        // A LDS reads
        short8 ah[2], al[2];
        #pragma unroll
        for (int rt = 0; rt < 2; ++rt) {
            int row = row0 + rt * 16 + lc;
            int lin = row * ASTR + ks * 64 + kg * 16;
            if (SWZ) lin ^= (row & 7) << 4;
            ah[rt] = *(const short8*)(Ahi + lin);
            al[rt] = *(const short8*)(Alo + lin);
        }
        #pragma unroll
        for (int rt = 0; rt < 2; ++rt)
        #pragma unroll
        for (int ctl = 0; ctl < 4; ++ctl) {
            acc[rt][ctl] = __builtin_amdgcn_mfma_f32_16x16x32_bf16(ah[rt], bh[ctl], acc[rt][ctl], 0, 0, 0);
            acc[rt][ctl] = __builtin_amdgcn_mfma_f32_16x16x32_bf16(ah[rt], bl[ctl], acc[rt][ctl], 0, 0, 0);
            acc[rt][ctl] = __builtin_amdgcn_mfma_f32_16x16x32_bf16(al[rt], bh[ctl], acc[rt][ctl], 0, 0, 0);
        }
    }
}

// relu + hi/lo split + swizzled store into h region ([64][512] bf16, stride 1024B)
__device__ __forceinline__ void store_h(char* Ohi, char* Olo,
                                        f32x4 (&acc)[2][4], int lane, int row0, int col0) {
    const int lc = lane & 15, kg = lane >> 4;
    #pragma unroll
    for (int rt = 0; rt < 2; ++rt)
    #pragma unroll
    for (int ctl = 0; ctl < 4; ++ctl)
    #pragma unroll
    for (int q = 0; q < 4; ++q) {
        int row = row0 + rt * 16 + kg * 4 + q;   // C layout: row=(lane>>4)*4+q
        int col = col0 + ctl * 16 + lc;          // C layout: col=lane&15
        float v = fmaxf(acc[rt][ctl][q], 0.f);
        unsigned short h = f2bf(v);
        unsigned short l = f2bf(v - bf2f(h));
        int lin = (row * 1024 + col * 2) ^ ((row & 7) << 4);
        *(unsigned short*)(Ohi + lin) = h;
        *(unsigned short*)(Olo + lin) = l;
    }
}

// layer-3 unit: one 16x16 col-tile (ct) x one 16-row tile (rt), K=512
__device__ __forceinline__ void l3_unit(const char* Hhi, const char* Hlo,
                                        const unsigned short* __restrict__ Bhi,
                                        const unsigned short* __restrict__ Blo,
                                        int u, int lane, f32x4& o)
{
    const int lc = lane & 15, kg = lane >> 4;
    const int ct = u >> 2, rt = u & 3;
    o = (f32x4){0.f, 0.f, 0.f, 0.f};
    const unsigned short* bh_p = Bhi + ((size_t)kg * L3_N + ct * 16 + lc) * 8;
    const unsigned short* bl_p = Blo + ((size_t)kg * L3_N + ct * 16 + lc) * 8;
    const size_t bstep = (size_t)4 * L3_N * 8;
    for (int ks = 0; ks < 16; ++ks) {
        int row = rt * 16 + lc;
        int lin = (row * 1024 + ks * 64 + kg * 16) ^ ((row & 7) << 4);
        short8 ah = *(const short8*)(Hhi + lin);
        short8 al = *(const short8*)(Hlo + lin);
        short8 bh = *(const short8*)(bh_p + (size_t)ks * bstep);
        short8 bl = *(const short8*)(bl_p + (size_t)ks * bstep);
        o = __builtin_amdgcn_mfma_f32_16x16x32_bf16(ah, bh, o, 0, 0, 0);
        o = __builtin_amdgcn_mfma_f32_16x16x32_bf16(ah, bl, o, 0, 0, 0);
        o = __builtin_amdgcn_mfma_f32_16x16x32_bf16(al, bh, o, 0, 0, 0);
    }
}

__device__ __forceinline__ void l3_store(float* os, const float* __restrict__ bias,
                                         int u, int lane, const f32x4& o) {
    const int lc = lane & 15, kg = lane >> 4;
    const int ct = u >> 2, rt = u & 3;
    int col = ct * 16 + lc;
    if (col < OUT_DIM) {
        #pragma unroll
        for (int q = 0; q < 4; ++q) {
            int row = rt * 16 + kg * 4 + q;
            os[row * 132 + col] = o[q] + bias[col];
        }
    }
}

// ---------------- fused MLP, split-bf16 MFMA, BM=64, 16 waves (32x64 per wave) ----------------
__launch_bounds__(MTHREADS)
__global__ void mlp_mfma_kernel(const float* __restrict__ state,
                                const float* __restrict__ action,
                                const float* __restrict__ eps,
                                const float* __restrict__ b1,
                                const float* __restrict__ b2,
                                const float* __restrict__ b3,
                                const unsigned short* __restrict__ w1hi, const unsigned short* __restrict__ w1lo,
                                const unsigned short* __restrict__ w2hi, const unsigned short* __restrict__ w2lo,
                                const unsigned short* __restrict__ w3hi, const unsigned short* __restrict__ w3lo,
                                const int* __restrict__ cnt, const int* __restrict__ bucket,
                                float* __restrict__ out) {
    __shared__ char smem[159744];
    char* xhi = smem;                    // [64][112] bf16, stride 224B (14336 B)
    char* xlo = smem + 14336;            // (14336 B)
    char* hhi = smem + 28672;            // [64][512] bf16 swizzled (65536 B) — h1 then h2
    char* hlo = smem + 94208;            // (65536 B)
    float* os = (float*)(smem + 28672);  // [64][132] fp32 (33792 B), overlays h after layer 3

    const int e    = blockIdx.x / TILES_PER_E;
    const int tile = blockIdx.x % TILES_PER_E;
    const int n    = cnt[e];
    const int m0   = tile * BM;
    if (m0 >= n) return;
    const int nrows = min(BM, n - m0);
    const int t = threadIdx.x;
    const int lane = t & 63;
    const int wv = t >> 6;
    const int row0 = (wv >> 3) * 32;     // 2 row-groups
    const int col0 = (wv & 7) * 64;      // 8 col-groups
    const int* brow = bucket + (size_t)e * B_ROWS;

    // ---- stage x = concat(state, action) hi/lo, 64x112 (cols>=80 zero), unswizzled ----
    for (int i = t; i < BM * 112; i += MTHREADS) {
        int r = i / 112, c = i % 112;
        int rb = brow[min(m0 + r, n - 1)];
        float v = 0.f;
        if (c < STATE_DIM)      v = state[(size_t)rb * STATE_DIM + c];
        else if (c < IN_DIM)    v = action[(size_t)rb * ACTION_DIM + (c - STATE_DIM)];
        unsigned short h = f2bf(v);
        unsigned short l = f2bf(v - bf2f(h));
        *(unsigned short*)(xhi + r * 224 + c * 2) = h;
        *(unsigned short*)(xlo + r * 224 + c * 2) = l;
    }
    __syncthreads();

    f32x4 acc[2][4];

    // ---- layer 1: h1 = relu(x @ W1 + b1), K=96, N=512 ----
    gemm_compute<224, false>(xhi, xlo, row0, 3,
        w1hi + (size_t)e * L1_K8 * HIDDEN * 8, w1lo + (size_t)e * L1_K8 * HIDDEN * 8,
        HIDDEN, b1 + (size_t)e * HIDDEN, acc, lane, col0);
    store_h(hhi, hlo, acc, lane, row0, col0);  // h region disjoint from x: no WAR hazard
    __syncthreads();

    // ---- layer 2: h2 = relu(h1 @ W2 + b2), K=512, N=512; h2 held in regs until barrier ----
    gemm_compute<1024, true>(hhi, hlo, row0, 16,
        w2hi + (size_t)e * L2_K8 * HIDDEN * 8, w2lo + (size_t)e * L2_K8 * HIDDEN * 8,
        HIDDEN, b2 + (size_t)e * HIDDEN, acc, lane, col0);
    __syncthreads();                           // all h1 reads complete
    store_h(hhi, hlo, acc, lane, row0, col0);  // overwrite h1 with h2
    __syncthreads();

    // ---- layer 3: o = h2 @ W3 + b3, K=512, N=144 (36 units over 16 waves) ----
    {
        const unsigned short* Bh = w3hi + (size_t)e * L3_K8 * L3_N * 8;
        const unsigned short* Bl = w3lo + (size_t)e * L3_K8 * L3_N * 8;
        const float* b3e = b3 + (size_t)e * OUT_DIM;
        f32x4 o0, o1, o2;
        l3_unit(hhi, hlo, Bh, Bl, wv, lane, o0);
        l3_unit(hhi, hlo, Bh, Bl, wv + 16, lane, o1);
        if (wv < 4) l3_unit(hhi, hlo, Bh, Bl, wv + 32, lane, o2);
        __syncthreads();                    // all h2 reads complete
        l3_store(os, b3e, wv, lane, o0);
        l3_store(os, b3e, wv + 16, lane, o1);
        if (wv < 4) l3_store(os, b3e, wv + 32, lane, o2);
    }
    __syncthreads();

    // ---- epilogue ----
    for (int i = t; i < BM * D_OUT; i += MTHREADS) {
        int r = i / D_OUT, c = i % D_OUT;
        if (r >= nrows) continue;
        int rb = brow[m0 + r];
        float mu = os[r * 132 + c];
        float ls = fminf(fmaxf(os[r * 132 + c + D_OUT], -20.f), 2.f);
        float y  = fmaf(expf(ls), eps[(size_t)rb * D_OUT + c], mu);
        if (c < STATE_DIM) {
            out[(size_t)rb * STATE_DIM + c] = state[(size_t)rb * STATE_DIM + c] + y;
        } else {
            out[(size_t)B_ROWS * STATE_DIM + rb] = y;
        }
    }
}

// ================= fallback fp32 path (used if ws too small) =================
#define FB_BM      16
#define FB_THREADS 256
#define FB_TILES   ((B_ROWS + FB_BM - 1) / FB_BM)

__launch_bounds__(FB_THREADS, 2)
__global__ void mlp_fp32_kernel(const float* __restrict__ state,
                                const float* __restrict__ action,
                                const float* __restrict__ eps,
                                const float* __restrict__ W1, const float* __restrict__ b1,
                                const float* __restrict__ W2, const float* __restrict__ b2,
                                const float* __restrict__ W3, const float* __restrict__ b3,
                                const int* __restrict__ cnt, const int* __restrict__ bucket,
                                float* __restrict__ out) {
    __shared__ float xs[FB_BM][IN_DIM];
    __shared__ float h1[FB_BM][HIDDEN];
    __shared__ float h2[FB_BM][HIDDEN];
    __shared__ float os[FB_BM][OUT_DIM];
    __shared__ int   rows[FB_BM];

    const int e    = blockIdx.x / FB_TILES;
    const int tile = blockIdx.x % FB_TILES;
    const int n    = cnt[e];
    const int m0   = tile * FB_BM;
    if (m0 >= n) return;
    const int nrows = min(FB_BM, n - m0);
    const int t = threadIdx.x;

    if (t < FB_BM) rows[t] = (t < nrows) ? bucket[e * B_ROWS + m0 + t] : bucket[e * B_ROWS + m0];
    __syncthreads();

    for (int i = t; i < FB_BM * IN_DIM; i += FB_THREADS) {
        int r = i / IN_DIM, c = i % IN_DIM;
        int rb = rows[r];
        xs[r][c] = (c < STATE_DIM) ? state[(size_t)rb * STATE_DIM + c]
                                   : action[(size_t)rb * ACTION_DIM + (c - STATE_DIM)];
    }
    __syncthreads();

    const int c0 = 2 * t;
    {
        const float* We = W1 + (size_t)e * IN_DIM * HIDDEN;
        float acc0[FB_BM], acc1[FB_BM];
        const float bias0 = b1[(size_t)e * HIDDEN + c0];
        const float bias1 = b1[(size_t)e * HIDDEN + c0 + 1];
        #pragma unroll
        for (int r = 0; r < FB_BM; ++r) { acc0[r] = bias0; acc1[r] = bias1; }
        for (int k = 0; k < IN_DIM; k += 4) {
            float2 w0 = *(const float2*)&We[(size_t)(k + 0) * HIDDEN + c0];
            float2 w1 = *(const float2*)&We[(size_t)(k + 1) * HIDDEN + c0];
            float2 w2 = *(const float2*)&We[(size_t)(k + 2) * HIDDEN + c0];
            float2 w3 = *(const float2*)&We[(size_t)(k + 3) * HIDDEN + c0];
            #pragma unroll
            for (int r = 0; r < FB_BM; ++r) {
                float4 x = *(const float4*)&xs[r][k];
                acc0[r] = fmaf(x.x, w0.x, acc0[r]); acc1[r] = fmaf(x.x, w0.y, acc1[r]);
                acc0[r] = fmaf(x.y, w1.x, acc0[r]); acc1[r] = fmaf(x.y, w1.y, acc1[r]);
                acc0[r] = fmaf(x.z, w2.x, acc0[r]); acc1[r] = fmaf(x.z, w2.y, acc1[r]);
                acc0[r] = fmaf(x.w, w3.x, acc0[r]); acc1[r] = fmaf(x.w, w3.y, acc1[r]);
            }
        }
        #pragma unroll
        for (int r = 0; r < FB_BM; ++r)
            *(float2*)&h1[r][c0] = make_float2(fmaxf(acc0[r], 0.f), fmaxf(acc1[r], 0.f));
    }
    __syncthreads();
    {
        const float* We = W2 + (size_t)e * HIDDEN * HIDDEN;
        float acc0[FB_BM], acc1[FB_BM];
        const float bias0 = b2[(size_t)e * HIDDEN + c0];
        const float bias1 = b2[(size_t)e * HIDDEN + c0 + 1];
        #pragma unroll
        for (int r = 0; r < FB_BM; ++r) { acc0[r] = bias0; acc1[r] = bias1; }
        for (int k = 0; k < HIDDEN; k += 4) {
            float2 w0 = *(const float2*)&We[(size_t)(k + 0) * HIDDEN + c0];
            float2 w1 = *(const float2*)&We[(size_t)(k + 1) * HIDDEN + c0];
            float2 w2 = *(const float2*)&We[(size_t)(k + 2) * HIDDEN + c0];
            float2 w3 = *(const float2*)&We[(size_t)(k + 3) * HIDDEN + c0];
            #pragma unroll
            for (int r = 0; r < FB_BM; ++r) {
                float4 x = *(const float4*)&h1[r][k];
                acc0[r] = fmaf(x.x, w0.x, acc0[r]); acc1[r] = fmaf(x.x, w0.y, acc1[r]);
                acc0[r] = fmaf(x.y, w1.x, acc0[r]); acc1[r] = fmaf(x.y, w1.y, acc1[r]);
                acc0[r] = fmaf(x.z, w2.x, acc0[r]); acc1[r] = fmaf(x.z, w2.y, acc1[r]);
                acc0[r] = fmaf(x.w, w3.x, acc0[r]); acc1[r] = fmaf(x.w, w3.y, acc1[r]);
            }
        }
        #pragma unroll
        for (int r = 0; r < FB_BM; ++r)
            *(float2*)&h2[r][c0] = make_float2(fmaxf(acc0[r], 0.f), fmaxf(acc1[r], 0.f));
    }
    __syncthreads();
    {
        const float* We = W3 + (size_t)e * HIDDEN * OUT_DIM;
        for (int i = t; i < FB_BM * OUT_DIM; i += FB_THREADS) {
            int r = i / OUT_DIM, c = i % OUT_DIM;
            float acc = b3[(size_t)e * OUT_DIM + c];
            for (int k = 0; k < HIDDEN; k += 4) {
                float4 h = *(const float4*)&h2[r][k];
                acc = fmaf(h.x, We[(size_t)(k + 0) * OUT_DIM + c], acc);
                acc = fmaf(h.y, We[(size_t)(k + 1) * OUT_DIM + c], acc);
                acc = fmaf(h.z, We[(size_t)(k + 2) * OUT_DIM + c], acc);
                acc = fmaf(h.w, We[(size_t)(k + 3) * OUT_DIM + c], acc);
            }
            os[r][c] = acc;
        }
    }
    __syncthreads();
    for (int i = t; i < FB_BM * D_OUT; i += FB_THREADS) {
        int r = i / D_OUT, c = i % D_OUT;
        if (r >= nrows) continue;
        int rb = rows[r];
        float mu = os[r][c];
        float ls = fminf(fmaxf(os[r][c + D_OUT], -20.f), 2.f);
        float y  = fmaf(expf(ls), eps[(size_t)rb * D_OUT + c], mu);
        if (c < STATE_DIM) out[(size_t)rb * STATE_DIM + c] = state[(size_t)rb * STATE_DIM + c] + y;
        else               out[(size_t)B_ROWS * STATE_DIM + rb] = y;
    }
}

extern "C" void kernel_launch(void* const* d_in, const int* in_sizes, int n_in,
                              void* d_out, int out_size, void* d_ws, size_t ws_size,
                              hipStream_t stream) {
    const float* state  = (const float*)d_in[0];
    const float* action = (const float*)d_in[1];
    const float* eps    = (const float*)d_in[2];
    const float* W1     = (const float*)d_in[3];
    const float* b1     = (const float*)d_in[4];
    const float* W2     = (const float*)d_in[5];
    const float* b2     = (const float*)d_in[6];
    const float* W3     = (const float*)d_in[7];
    const float* b3     = (const float*)d_in[8];
    const int*   idx    = (const int*)d_in[9];
    float* out = (float*)d_out;

    int* cnt    = (int*)((char*)d_ws + OFF_CNT);
    int* bucket = (int*)((char*)d_ws + OFF_BUCKET);

    hipMemsetAsync(cnt, 0, ENSEMBLE * sizeof(int), stream);
    bucket_kernel<<<(B_ROWS + 255) / 256, 256, 0, stream>>>(idx, cnt, bucket);

    if (ws_size >= WS_NEEDED) {
        unsigned short* w1hi = (unsigned short*)((char*)d_ws + OFF_W1HI);
        unsigned short* w1lo = (unsigned short*)((char*)d_ws + OFF_W1LO);
        unsigned short* w2hi = (unsigned short*)((char*)d_ws + OFF_W2HI);
        unsigned short* w2lo = (unsigned short*)((char*)d_ws + OFF_W2LO);
        unsigned short* w3hi = (unsigned short*)((char*)d_ws + OFF_W3HI);
        unsigned short* w3lo = (unsigned short*)((char*)d_ws + OFF_W3LO);

        const int groups = TOP_K * (L1_K8 * HIDDEN + L2_K8 * HIDDEN + L3_K8 * L3_N);
        pack_kernel<<<(groups + 255) / 256, 256, 0, stream>>>(
            W1, W2, W3, w1hi, w1lo, w2hi, w2lo, w3hi, w3lo);

        mlp_mfma_kernel<<<TOP_K * TILES_PER_E, MTHREADS, 0, stream>>>(
            state, action, eps, b1, b2, b3,
            w1hi, w1lo, w2hi, w2lo, w3hi, w3lo, cnt, bucket, out);
    } else {
        mlp_fp32_kernel<<<TOP_K * FB_TILES, FB_THREADS, 0, stream>>>(
            state, action, eps, W1, b1, W2, b2, W3, b3, cnt, bucket, out);
    }
}

// Round 5
// 168.883 us; speedup vs baseline: 4.6866x; 1.0874x over previous
//
#include <hip/hip_runtime.h>
#include <math.h>

#define B_ROWS     32768
#define STATE_DIM  64
#define ACTION_DIM 16
#define HIDDEN     512
#define ENSEMBLE   7
#define TOP_K      5
#define IN_DIM     80    // STATE_DIM + ACTION_DIM
#define OUT_DIM    130   // 2*(STATE_DIM+1)
#define D_OUT      65    // STATE_DIM+1

// ---- MFMA kernel geometry ----
#define BM         64
#define MTHREADS   1024                          // 16 waves = 2 row-groups x 8 col-groups
#define TILES_PER_E ((B_ROWS + BM - 1) / BM)     // 512

// ---- packed weight dims ----
#define L1_K8 12      // K=96 (real 80)
#define L2_K8 64      // K=512
#define L3_K8 64      // K=512
#define L3_N  144     // N=130 padded to 9 col-tiles

#define N_W1 (TOP_K * L1_K8 * HIDDEN * 8)
#define N_W2 (TOP_K * L2_K8 * HIDDEN * 8)
#define N_W3 (TOP_K * L3_K8 * L3_N * 8)

#define OFF_CNT    0
#define OFF_BUCKET 256
#define OFF_W1     (OFF_BUCKET + ENSEMBLE * B_ROWS * 4)
#define OFF_W2     (OFF_W1 + N_W1 * 2)
#define OFF_W3     (OFF_W2 + N_W2 * 2)
#define WS_NEEDED  ((size_t)(OFF_W3 + N_W3 * 2))

typedef __attribute__((ext_vector_type(8))) _Float16 half8;
typedef __attribute__((ext_vector_type(4))) float f32x4;

// ---------------- bucket rows by ensemble index (wave-aggregated atomics) ----------------
__global__ void bucket_kernel(const int* __restrict__ idx,
                              int* __restrict__ cnt,
                              int* __restrict__ bucket) {
    int b = blockIdx.x * blockDim.x + threadIdx.x;
    int lane = threadIdx.x & 63;
    int e = -1;
    if (b < B_ROWS) e = min(max(idx[b], 0), TOP_K - 1);
    #pragma unroll
    for (int ev = 0; ev < TOP_K; ++ev) {
        unsigned long long m = __ballot(e == ev);
        if (m == 0ull) continue;
        int leader = __ffsll((unsigned long long)m) - 1;
        int base = 0;
        if (lane == leader) base = atomicAdd(&cnt[ev], __popcll(m));
        base = __shfl(base, leader);
        if (e == ev) {
            int rank = __popcll(m & ((1ull << lane) - 1ull));
            bucket[ev * B_ROWS + base + rank] = b;
        }
    }
}

// ---------------- pack weights fp32 -> fp16 MFMA layout ----------------
// layout: [e][k8][n][8] so a B-fragment (8 consecutive k of one column) is 16B contiguous
__global__ void pack_kernel(const float* __restrict__ W1, const float* __restrict__ W2,
                            const float* __restrict__ W3,
                            _Float16* __restrict__ w1, _Float16* __restrict__ w2,
                            _Float16* __restrict__ w3) {
    const int G1 = L1_K8 * HIDDEN;   // 6144
    const int G2 = L2_K8 * HIDDEN;   // 32768
    const int G3 = L3_K8 * L3_N;     // 9216
    const int GPE = G1 + G2 + G3;    // 48128
    int g = blockIdx.x * blockDim.x + threadIdx.x;
    if (g >= TOP_K * GPE) return;
    int e = g / GPE, r = g % GPE;

    const float* src; _Float16* dd;
    size_t dst; int k8, n, Kreal, Nreal, srcN;
    if (r < G1) {
        k8 = r / HIDDEN; n = r % HIDDEN;
        src = W1 + (size_t)e * IN_DIM * HIDDEN; Kreal = IN_DIM; Nreal = HIDDEN; srcN = HIDDEN;
        dd = w1; dst = (((size_t)e * L1_K8 + k8) * HIDDEN + n) * 8;
    } else if (r < G1 + G2) {
        int rr = r - G1; k8 = rr / HIDDEN; n = rr % HIDDEN;
        src = W2 + (size_t)e * HIDDEN * HIDDEN; Kreal = HIDDEN; Nreal = HIDDEN; srcN = HIDDEN;
        dd = w2; dst = (((size_t)e * L2_K8 + k8) * HIDDEN + n) * 8;
    } else {
        int rr = r - G1 - G2; k8 = rr / L3_N; n = rr % L3_N;
        src = W3 + (size_t)e * HIDDEN * OUT_DIM; Kreal = HIDDEN; Nreal = OUT_DIM; srcN = OUT_DIM;
        dd = w3; dst = (((size_t)e * L3_K8 + k8) * L3_N + n) * 8;
    }
    half8 hv;
    #pragma unroll
    for (int j = 0; j < 8; ++j) {
        int k = k8 * 8 + j;
        float v = (k < Kreal && n < Nreal) ? src[(size_t)k * srcN + n] : 0.f;
        hv[j] = (_Float16)v;
    }
    *(half8*)(dd + dst) = hv;
}

// ---------------- GEMM compute: 32 rows x 64 cols per wave, B explicitly double-buffered ----
// A in LDS (hi/lo fp16 planes, row stride ASTR bytes, optional XOR swizzle);
// B packed [k8][Bn][8] fp16 in global.
template<int ASTR, bool SWZ>
__device__ __forceinline__ void gemm_compute(
    const char* Ahi, const char* Alo, int row0, int ksteps,
    const _Float16* __restrict__ B, int Bn, const float* __restrict__ bias,
    f32x4 (&acc)[2][4], int lane, int col0)
{
    const int lc = lane & 15, kg = lane >> 4;
    #pragma unroll
    for (int ctl = 0; ctl < 4; ++ctl) {
        float b = bias[col0 + ctl * 16 + lc];
        #pragma unroll
        for (int rt = 0; rt < 2; ++rt) acc[rt][ctl] = (f32x4){b, b, b, b};
    }
    const size_t bstep = (size_t)4 * Bn * 8;   // elements per k-step
    const _Float16* bp = B + ((size_t)kg * Bn + col0 + lc) * 8;

    half8 bc[4], bn[4];
    #pragma unroll
    for (int ctl = 0; ctl < 4; ++ctl) bc[ctl] = *(const half8*)(bp + ctl * 128);

    for (int ks = 0; ks < ksteps; ++ks) {
        if (ks + 1 < ksteps) {
            const _Float16* pn = bp + (size_t)(ks + 1) * bstep;
            #pragma unroll
            for (int ctl = 0; ctl < 4; ++ctl) bn[ctl] = *(const half8*)(pn + ctl * 128);
        }
        half8 ah[2], al[2];
        #pragma unroll
        for (int rt = 0; rt < 2; ++rt) {
            int row = row0 + rt * 16 + lc;
            int lin = row * ASTR + ks * 64 + kg * 16;
            if (SWZ) lin ^= (row & 7) << 4;
            ah[rt] = *(const half8*)(Ahi + lin);
            al[rt] = *(const half8*)(Alo + lin);
        }
        #pragma unroll
        for (int rt = 0; rt < 2; ++rt)
        #pragma unroll
        for (int ctl = 0; ctl < 4; ++ctl) {
            acc[rt][ctl] = __builtin_amdgcn_mfma_f32_16x16x32_f16(ah[rt], bc[ctl], acc[rt][ctl], 0, 0, 0);
            acc[rt][ctl] = __builtin_amdgcn_mfma_f32_16x16x32_f16(al[rt], bc[ctl], acc[rt][ctl], 0, 0, 0);
        }
        #pragma unroll
        for (int ctl = 0; ctl < 4; ++ctl) bc[ctl] = bn[ctl];
    }
}

// relu + hi/lo fp16 split + swizzled store into h region ([64][512] fp16, stride 1024B)
__device__ __forceinline__ void store_h(char* Ohi, char* Olo,
                                        f32x4 (&acc)[2][4], int lane, int row0, int col0) {
    const int lc = lane & 15, kg = lane >> 4;
    #pragma unroll
    for (int rt = 0; rt < 2; ++rt)
    #pragma unroll
    for (int ctl = 0; ctl < 4; ++ctl)
    #pragma unroll
    for (int q = 0; q < 4; ++q) {
        int row = row0 + rt * 16 + kg * 4 + q;   // C layout: row=(lane>>4)*4+q
        int col = col0 + ctl * 16 + lc;          // C layout: col=lane&15
        float v = fmaxf(acc[rt][ctl][q], 0.f);
        _Float16 h = (_Float16)v;
        _Float16 l = (_Float16)(v - (float)h);
        int lin = (row * 1024 + col * 2) ^ ((row & 7) << 4);
        *(_Float16*)(Ohi + lin) = h;
        *(_Float16*)(Olo + lin) = l;
    }
}

__device__ __forceinline__ void l3_store(float* os, const float* __restrict__ bias,
                                         int ct, int rt, int lane, const f32x4& o) {
    const int lc = lane & 15, kg = lane >> 4;
    int col = ct * 16 + lc;
    if (col < OUT_DIM) {
        #pragma unroll
        for (int q = 0; q < 4; ++q) {
            int row = rt * 16 + kg * 4 + q;
            os[row * 132 + col] = o[q] + bias[col];
        }
    }
}

// ---------------- fused MLP, split-fp16 MFMA, BM=64, 16 waves (32x64 per wave) ----------------
__launch_bounds__(MTHREADS)
__global__ void mlp_mfma_kernel(const float* __restrict__ state,
                                const float* __restrict__ action,
                                const float* __restrict__ eps,
                                const float* __restrict__ b1,
                                const float* __restrict__ b2,
                                const float* __restrict__ b3,
                                const _Float16* __restrict__ w1,
                                const _Float16* __restrict__ w2,
                                const _Float16* __restrict__ w3,
                                const int* __restrict__ cnt, const int* __restrict__ bucket,
                                float* __restrict__ out) {
    __shared__ char smem[159744];
    char* xhi = smem;                    // [64][112] fp16, stride 224B (14336 B)
    char* xlo = smem + 14336;            // (14336 B)
    char* hhi = smem + 28672;            // [64][512] fp16 swizzled (65536 B) — h1 then h2
    char* hlo = smem + 94208;            // (65536 B)
    float* os = (float*)(smem + 28672);  // [64][132] fp32 (33792 B), overlays h after layer 3

    const int e    = blockIdx.x / TILES_PER_E;
    const int tile = blockIdx.x % TILES_PER_E;
    const int n    = cnt[e];
    const int m0   = tile * BM;
    if (m0 >= n) return;
    const int nrows = min(BM, n - m0);
    const int t = threadIdx.x;
    const int lane = t & 63;
    const int wv = t >> 6;
    const int row0 = (wv >> 3) * 32;     // 2 row-groups
    const int col0 = (wv & 7) * 64;      // 8 col-groups
    const int* brow = bucket + (size_t)e * B_ROWS;

    // ---- stage x = concat(state, action) hi/lo fp16, 64x112 (cols>=80 zero) ----
    for (int i = t; i < BM * 112; i += MTHREADS) {
        int r = i / 112, c = i % 112;
        int rb = brow[min(m0 + r, n - 1)];
        float v = 0.f;
        if (c < STATE_DIM)      v = state[(size_t)rb * STATE_DIM + c];
        else if (c < IN_DIM)    v = action[(size_t)rb * ACTION_DIM + (c - STATE_DIM)];
        _Float16 h = (_Float16)v;
        _Float16 l = (_Float16)(v - (float)h);
        *(_Float16*)(xhi + r * 224 + c * 2) = h;
        *(_Float16*)(xlo + r * 224 + c * 2) = l;
    }
    __syncthreads();

    f32x4 acc[2][4];

    // ---- layer 1: h1 = relu(x @ W1 + b1), K=96, N=512 ----
    gemm_compute<224, false>(xhi, xlo, row0, 3,
        w1 + (size_t)e * L1_K8 * HIDDEN * 8,
        HIDDEN, b1 + (size_t)e * HIDDEN, acc, lane, col0);
    store_h(hhi, hlo, acc, lane, row0, col0);  // h region disjoint from x: no WAR hazard
    __syncthreads();

    // ---- layer 2: h2 = relu(h1 @ W2 + b2), K=512, N=512; h2 held in regs until barrier ----
    gemm_compute<1024, true>(hhi, hlo, row0, 16,
        w2 + (size_t)e * L2_K8 * HIDDEN * 8,
        HIDDEN, b2 + (size_t)e * HIDDEN, acc, lane, col0);
    __syncthreads();                           // all h1 reads complete
    store_h(hhi, hlo, acc, lane, row0, col0);  // overwrite h1 with h2
    __syncthreads();

    // ---- layer 3: o = h2 @ W3 + b3, K=512, N=144; wave wv: rt=wv&3, ct=wv>>2 (+4, +8) ----
    {
        const _Float16* Bw = w3 + (size_t)e * L3_K8 * L3_N * 8;
        const float* b3e = b3 + (size_t)e * OUT_DIM;
        const int lc = lane & 15, kg = lane >> 4;
        const int rt = wv & 3;
        const int ct0 = wv >> 2;             // 0..3
        const bool third = (wv < 4);         // waves 0..3 also do ct=8 with rt=wv
        f32x4 o0 = {0.f,0.f,0.f,0.f}, o1 = o0, o2 = o0;
        const size_t bstep = (size_t)4 * L3_N * 8;
        const _Float16* bp0 = Bw + ((size_t)kg * L3_N + ct0 * 16 + lc) * 8;
        const _Float16* bp1 = Bw + ((size_t)kg * L3_N + (ct0 + 4) * 16 + lc) * 8;
        const _Float16* bp2 = Bw + ((size_t)kg * L3_N + 8 * 16 + lc) * 8;
        for (int ks = 0; ks < 16; ++ks) {
            int row = rt * 16 + lc;
            int lin = (row * 1024 + ks * 64 + kg * 16) ^ ((row & 7) << 4);
            half8 ah = *(const half8*)(hhi + lin);
            half8 al = *(const half8*)(hlo + lin);
            half8 b0 = *(const half8*)(bp0 + (size_t)ks * bstep);
            half8 b1v = *(const half8*)(bp1 + (size_t)ks * bstep);
            o0 = __builtin_amdgcn_mfma_f32_16x16x32_f16(ah, b0, o0, 0, 0, 0);
            o0 = __builtin_amdgcn_mfma_f32_16x16x32_f16(al, b0, o0, 0, 0, 0);
            o1 = __builtin_amdgcn_mfma_f32_16x16x32_f16(ah, b1v, o1, 0, 0, 0);
            o1 = __builtin_amdgcn_mfma_f32_16x16x32_f16(al, b1v, o1, 0, 0, 0);
            if (third) {
                half8 b2v = *(const half8*)(bp2 + (size_t)ks * bstep);
                o2 = __builtin_amdgcn_mfma_f32_16x16x32_f16(ah, b2v, o2, 0, 0, 0);
                o2 = __builtin_amdgcn_mfma_f32_16x16x32_f16(al, b2v, o2, 0, 0, 0);
            }
        }
        __syncthreads();                    // all h2 reads complete (os overlays h)
        l3_store(os, b3e, ct0,     rt, lane, o0);
        l3_store(os, b3e, ct0 + 4, rt, lane, o1);
        if (third) l3_store(os, b3e, 8, rt, lane, o2);
    }
    __syncthreads();

    // ---- epilogue ----
    for (int i = t; i < BM * D_OUT; i += MTHREADS) {
        int r = i / D_OUT, c = i % D_OUT;
        if (r >= nrows) continue;
        int rb = brow[m0 + r];
        float mu = os[r * 132 + c];
        float ls = fminf(fmaxf(os[r * 132 + c + D_OUT], -20.f), 2.f);
        float y  = fmaf(expf(ls), eps[(size_t)rb * D_OUT + c], mu);
        if (c < STATE_DIM) {
            out[(size_t)rb * STATE_DIM + c] = state[(size_t)rb * STATE_DIM + c] + y;
        } else {
            out[(size_t)B_ROWS * STATE_DIM + rb] = y;
        }
    }
}

// ================= fallback fp32 path (used if ws too small) =================
#define FB_BM      16
#define FB_THREADS 256
#define FB_TILES   ((B_ROWS + FB_BM - 1) / FB_BM)

__launch_bounds__(FB_THREADS, 2)
__global__ void mlp_fp32_kernel(const float* __restrict__ state,
                                const float* __restrict__ action,
                                const float* __restrict__ eps,
                                const float* __restrict__ W1, const float* __restrict__ b1,
                                const float* __restrict__ W2, const float* __restrict__ b2,
                                const float* __restrict__ W3, const float* __restrict__ b3,
                                const int* __restrict__ cnt, const int* __restrict__ bucket,
                                float* __restrict__ out) {
    __shared__ float xs[FB_BM][IN_DIM];
    __shared__ float h1[FB_BM][HIDDEN];
    __shared__ float h2[FB_BM][HIDDEN];
    __shared__ float os[FB_BM][OUT_DIM];
    __shared__ int   rows[FB_BM];

    const int e    = blockIdx.x / FB_TILES;
    const int tile = blockIdx.x % FB_TILES;
    const int n    = cnt[e];
    const int m0   = tile * FB_BM;
    if (m0 >= n) return;
    const int nrows = min(FB_BM, n - m0);
    const int t = threadIdx.x;

    if (t < FB_BM) rows[t] = (t < nrows) ? bucket[e * B_ROWS + m0 + t] : bucket[e * B_ROWS + m0];
    __syncthreads();

    for (int i = t; i < FB_BM * IN_DIM; i += FB_THREADS) {
        int r = i / IN_DIM, c = i % IN_DIM;
        int rb = rows[r];
        xs[r][c] = (c < STATE_DIM) ? state[(size_t)rb * STATE_DIM + c]
                                   : action[(size_t)rb * ACTION_DIM + (c - STATE_DIM)];
    }
    __syncthreads();

    const int c0 = 2 * t;
    {
        const float* We = W1 + (size_t)e * IN_DIM * HIDDEN;
        float acc0[FB_BM], acc1[FB_BM];
        const float bias0 = b1[(size_t)e * HIDDEN + c0];
        const float bias1 = b1[(size_t)e * HIDDEN + c0 + 1];
        #pragma unroll
        for (int r = 0; r < FB_BM; ++r) { acc0[r] = bias0; acc1[r] = bias1; }
        for (int k = 0; k < IN_DIM; k += 4) {
            float2 w0 = *(const float2*)&We[(size_t)(k + 0) * HIDDEN + c0];
            float2 w1v = *(const float2*)&We[(size_t)(k + 1) * HIDDEN + c0];
            float2 w2v = *(const float2*)&We[(size_t)(k + 2) * HIDDEN + c0];
            float2 w3v = *(const float2*)&We[(size_t)(k + 3) * HIDDEN + c0];
            #pragma unroll
            for (int r = 0; r < FB_BM; ++r) {
                float4 x = *(const float4*)&xs[r][k];
                acc0[r] = fmaf(x.x, w0.x, acc0[r]); acc1[r] = fmaf(x.x, w0.y, acc1[r]);
                acc0[r] = fmaf(x.y, w1v.x, acc0[r]); acc1[r] = fmaf(x.y, w1v.y, acc1[r]);
                acc0[r] = fmaf(x.z, w2v.x, acc0[r]); acc1[r] = fmaf(x.z, w2v.y, acc1[r]);
                acc0[r] = fmaf(x.w, w3v.x, acc0[r]); acc1[r] = fmaf(x.w, w3v.y, acc1[r]);
            }
        }
        #pragma unroll
        for (int r = 0; r < FB_BM; ++r)
            *(float2*)&h1[r][c0] = make_float2(fmaxf(acc0[r], 0.f), fmaxf(acc1[r], 0.f));
    }
    __syncthreads();
    {
        const float* We = W2 + (size_t)e * HIDDEN * HIDDEN;
        float acc0[FB_BM], acc1[FB_BM];
        const float bias0 = b2[(size_t)e * HIDDEN + c0];
        const float bias1 = b2[(size_t)e * HIDDEN + c0 + 1];
        #pragma unroll
        for (int r = 0; r < FB_BM; ++r) { acc0[r] = bias0; acc1[r] = bias1; }
        for (int k = 0; k < HIDDEN; k += 4) {
            float2 w0 = *(const float2*)&We[(size_t)(k + 0) * HIDDEN + c0];
            float2 w1v = *(const float2*)&We[(size_t)(k + 1) * HIDDEN + c0];
            float2 w2v = *(const float2*)&We[(size_t)(k + 2) * HIDDEN + c0];
            float2 w3v = *(const float2*)&We[(size_t)(k + 3) * HIDDEN + c0];
            #pragma unroll
            for (int r = 0; r < FB_BM; ++r) {
                float4 x = *(const float4*)&h1[r][k];
                acc0[r] = fmaf(x.x, w0.x, acc0[r]); acc1[r] = fmaf(x.x, w0.y, acc1[r]);
                acc0[r] = fmaf(x.y, w1v.x, acc0[r]); acc1[r] = fmaf(x.y, w1v.y, acc1[r]);
                acc0[r] = fmaf(x.z, w2v.x, acc0[r]); acc1[r] = fmaf(x.z, w2v.y, acc1[r]);
                acc0[r] = fmaf(x.w, w3v.x, acc0[r]); acc1[r] = fmaf(x.w, w3v.y, acc1[r]);
            }
        }
        #pragma unroll
        for (int r = 0; r < FB_BM; ++r)
            *(float2*)&h2[r][c0] = make_float2(fmaxf(acc0[r], 0.f), fmaxf(acc1[r], 0.f));
    }
    __syncthreads();
    {
        const float* We = W3 + (size_t)e * HIDDEN * OUT_DIM;
        for (int i = t; i < FB_BM * OUT_DIM; i += FB_THREADS) {
            int r = i / OUT_DIM, c = i % OUT_DIM;
            float acc = b3[(size_t)e * OUT_DIM + c];
            for (int k = 0; k < HIDDEN; k += 4) {
                float4 h = *(const float4*)&h2[r][k];
                acc = fmaf(h.x, We[(size_t)(k + 0) * OUT_DIM + c], acc);
                acc = fmaf(h.y, We[(size_t)(k + 1) * OUT_DIM + c], acc);
                acc = fmaf(h.z, We[(size_t)(k + 2) * OUT_DIM + c], acc);
                acc = fmaf(h.w, We[(size_t)(k + 3) * OUT_DIM + c], acc);
            }
            os[r][c] = acc;
        }
    }
    __syncthreads();
    for (int i = t; i < FB_BM * D_OUT; i += FB_THREADS) {
        int r = i / D_OUT, c = i % D_OUT;
        if (r >= nrows) continue;
        int rb = rows[r];
        float mu = os[r][c];
        float ls = fminf(fmaxf(os[r][c + D_OUT], -20.f), 2.f);
        float y  = fmaf(expf(ls), eps[(size_t)rb * D_OUT + c], mu);
        if (c < STATE_DIM) out[(size_t)rb * STATE_DIM + c] = state[(size_t)rb * STATE_DIM + c] + y;
        else               out[(size_t)B_ROWS * STATE_DIM + rb] = y;
    }
}

extern "C" void kernel_launch(void* const* d_in, const int* in_sizes, int n_in,
                              void* d_out, int out_size, void* d_ws, size_t ws_size,
                              hipStream_t stream) {
    const float* state  = (const float*)d_in[0];
    const float* action = (const float*)d_in[1];
    const float* eps    = (const float*)d_in[2];
    const float* W1     = (const float*)d_in[3];
    const float* b1     = (const float*)d_in[4];
    const float* W2     = (const float*)d_in[5];
    const float* b2     = (const float*)d_in[6];
    const float* W3     = (const float*)d_in[7];
    const float* b3     = (const float*)d_in[8];
    const int*   idx    = (const int*)d_in[9];
    float* out = (float*)d_out;

    int* cnt    = (int*)((char*)d_ws + OFF_CNT);
    int* bucket = (int*)((char*)d_ws + OFF_BUCKET);

    hipMemsetAsync(cnt, 0, ENSEMBLE * sizeof(int), stream);
    bucket_kernel<<<(B_ROWS + 255) / 256, 256, 0, stream>>>(idx, cnt, bucket);

    if (ws_size >= WS_NEEDED) {
        _Float16* w1 = (_Float16*)((char*)d_ws + OFF_W1);
        _Float16* w2 = (_Float16*)((char*)d_ws + OFF_W2);
        _Float16* w3 = (_Float16*)((char*)d_ws + OFF_W3);

        const int groups = TOP_K * (L1_K8 * HIDDEN + L2_K8 * HIDDEN + L3_K8 * L3_N);
        pack_kernel<<<(groups + 255) / 256, 256, 0, stream>>>(W1, W2, W3, w1, w2, w3);

        mlp_mfma_kernel<<<TOP_K * TILES_PER_E, MTHREADS, 0, stream>>>(
            state, action, eps, b1, b2, b3, w1, w2, w3, cnt, bucket, out);
    } else {
        mlp_fp32_kernel<<<TOP_K * FB_TILES, FB_THREADS, 0, stream>>>(
            state, action, eps, W1, b1, W2, b2, W3, b3, cnt, bucket, out);
    }
}

// Round 6
// 123.490 us; speedup vs baseline: 6.4093x; 1.3676x over previous
//
#include <hip/hip_runtime.h>
#include <math.h>

#define B_ROWS     32768
#define STATE_DIM  64
#define ACTION_DIM 16
#define HIDDEN     512
#define ENSEMBLE   7
#define TOP_K      5
#define IN_DIM     80    // STATE_DIM + ACTION_DIM
#define OUT_DIM    130   // 2*(STATE_DIM+1)
#define D_OUT      65    // STATE_DIM+1

// ---- MFMA kernel geometry ----
#define BM         32
#define MTHREADS   512                           // 8 waves, each 32 rows x 64 cols
#define TILES_PER_E ((B_ROWS + BM - 1) / BM)     // 1024

// ---- packed weight dims ----
#define L1_K8 12      // K=96 (real 80)
#define L2_K8 64      // K=512
#define L3_K8 64      // K=512
#define L3_N  144     // N=130 padded to 9 col-tiles

#define N_W1 (TOP_K * L1_K8 * HIDDEN * 8)
#define N_W2 (TOP_K * L2_K8 * HIDDEN * 8)
#define N_W3 (TOP_K * L3_K8 * L3_N * 8)

#define OFF_CNT    0
#define OFF_BUCKET 256
#define OFF_W1     (OFF_BUCKET + ENSEMBLE * B_ROWS * 4)
#define OFF_W2     (OFF_W1 + N_W1 * 2)
#define OFF_W3     (OFF_W2 + N_W2 * 2)
#define WS_NEEDED  ((size_t)(OFF_W3 + N_W3 * 2))

// prep kernel: first blocks bucket, rest pack
#define BUCKET_BLOCKS ((B_ROWS + 255) / 256)                     // 128
#define PACK_G        (TOP_K * (L1_K8*HIDDEN + L2_K8*HIDDEN + L3_K8*L3_N))  // 240640
#define PACK_BLOCKS   ((PACK_G + 255) / 256)                     // 940

typedef __attribute__((ext_vector_type(8))) _Float16 half8;
typedef __attribute__((ext_vector_type(4))) float f32x4;

// ---------------- prep: bucket rows + pack weights (fused, one launch) ----------------
__global__ void prep_kernel(const int* __restrict__ idx,
                            int* __restrict__ cnt,
                            int* __restrict__ bucket,
                            const float* __restrict__ W1, const float* __restrict__ W2,
                            const float* __restrict__ W3,
                            _Float16* __restrict__ w1, _Float16* __restrict__ w2,
                            _Float16* __restrict__ w3) {
    if (blockIdx.x < BUCKET_BLOCKS) {
        // ---- bucket rows by ensemble index (wave-aggregated atomics) ----
        int b = blockIdx.x * 256 + threadIdx.x;
        int lane = threadIdx.x & 63;
        int e = -1;
        if (b < B_ROWS) e = min(max(idx[b], 0), TOP_K - 1);
        #pragma unroll
        for (int ev = 0; ev < TOP_K; ++ev) {
            unsigned long long m = __ballot(e == ev);
            if (m == 0ull) continue;
            int leader = __ffsll((unsigned long long)m) - 1;
            int base = 0;
            if (lane == leader) base = atomicAdd(&cnt[ev], __popcll(m));
            base = __shfl(base, leader);
            if (e == ev) {
                int rank = __popcll(m & ((1ull << lane) - 1ull));
                bucket[ev * B_ROWS + base + rank] = b;
            }
        }
        return;
    }
    // ---- pack weights fp32 -> fp16, layout [e][k8][n][8] ----
    const int G1 = L1_K8 * HIDDEN;   // 6144
    const int G2 = L2_K8 * HIDDEN;   // 32768
    const int G3 = L3_K8 * L3_N;     // 9216
    const int GPE = G1 + G2 + G3;    // 48128
    int g = (blockIdx.x - BUCKET_BLOCKS) * 256 + threadIdx.x;
    if (g >= TOP_K * GPE) return;
    int e = g / GPE, r = g % GPE;

    const float* src; _Float16* dd;
    size_t dst; int k8, n, Kreal, Nreal, srcN;
    if (r < G1) {
        k8 = r / HIDDEN; n = r % HIDDEN;
        src = W1 + (size_t)e * IN_DIM * HIDDEN; Kreal = IN_DIM; Nreal = HIDDEN; srcN = HIDDEN;
        dd = w1; dst = (((size_t)e * L1_K8 + k8) * HIDDEN + n) * 8;
    } else if (r < G1 + G2) {
        int rr = r - G1; k8 = rr / HIDDEN; n = rr % HIDDEN;
        src = W2 + (size_t)e * HIDDEN * HIDDEN; Kreal = HIDDEN; Nreal = HIDDEN; srcN = HIDDEN;
        dd = w2; dst = (((size_t)e * L2_K8 + k8) * HIDDEN + n) * 8;
    } else {
        int rr = r - G1 - G2; k8 = rr / L3_N; n = rr % L3_N;
        src = W3 + (size_t)e * HIDDEN * OUT_DIM; Kreal = HIDDEN; Nreal = OUT_DIM; srcN = OUT_DIM;
        dd = w3; dst = (((size_t)e * L3_K8 + k8) * L3_N + n) * 8;
    }
    half8 hv;
    #pragma unroll
    for (int j = 0; j < 8; ++j) {
        int k = k8 * 8 + j;
        float v = (k < Kreal && n < Nreal) ? src[(size_t)k * srcN + n] : 0.f;
        hv[j] = (_Float16)v;
    }
    *(half8*)(dd + dst) = hv;
}

// ---------------- GEMM compute: 32 rows x 64 cols per wave, B double-buffered ----------------
// A in LDS (fp16, row stride ASTR bytes, optional XOR swizzle); B packed [k8][Bn][8] fp16.
template<int ASTR, bool SWZ>
__device__ __forceinline__ void gemm_compute(
    const char* A, int ksteps,
    const _Float16* __restrict__ B, int Bn, const float* __restrict__ bias,
    f32x4 (&acc)[2][4], int lane, int col0)
{
    const int lc = lane & 15, kg = lane >> 4;
    #pragma unroll
    for (int ctl = 0; ctl < 4; ++ctl) {
        float b = bias[col0 + ctl * 16 + lc];
        #pragma unroll
        for (int rt = 0; rt < 2; ++rt) acc[rt][ctl] = (f32x4){b, b, b, b};
    }
    const size_t bstep = (size_t)4 * Bn * 8;   // elements per k-step (K advances 32)
    const _Float16* bp = B + ((size_t)kg * Bn + col0 + lc) * 8;

    half8 bc[4], bn[4];
    #pragma unroll
    for (int ctl = 0; ctl < 4; ++ctl) bc[ctl] = *(const half8*)(bp + ctl * 128);

    for (int ks = 0; ks < ksteps; ++ks) {
        if (ks + 1 < ksteps) {
            const _Float16* pn = bp + (size_t)(ks + 1) * bstep;
            #pragma unroll
            for (int ctl = 0; ctl < 4; ++ctl) bn[ctl] = *(const half8*)(pn + ctl * 128);
        }
        half8 ah[2];
        #pragma unroll
        for (int rt = 0; rt < 2; ++rt) {
            int row = rt * 16 + lc;
            int lin = row * ASTR + ks * 64 + kg * 16;
            if (SWZ) lin ^= (row & 7) << 4;
            ah[rt] = *(const half8*)(A + lin);
        }
        #pragma unroll
        for (int rt = 0; rt < 2; ++rt)
        #pragma unroll
        for (int ctl = 0; ctl < 4; ++ctl)
            acc[rt][ctl] = __builtin_amdgcn_mfma_f32_16x16x32_f16(ah[rt], bc[ctl], acc[rt][ctl], 0, 0, 0);
        #pragma unroll
        for (int ctl = 0; ctl < 4; ++ctl) bc[ctl] = bn[ctl];
    }
}

// relu + fp16 + swizzled store into h region ([32][512] fp16, stride 1024B)
__device__ __forceinline__ void store_h(char* O, f32x4 (&acc)[2][4], int lane, int col0) {
    const int lc = lane & 15, kg = lane >> 4;
    #pragma unroll
    for (int rt = 0; rt < 2; ++rt)
    #pragma unroll
    for (int ctl = 0; ctl < 4; ++ctl)
    #pragma unroll
    for (int q = 0; q < 4; ++q) {
        int row = rt * 16 + kg * 4 + q;          // C layout: row=(lane>>4)*4+q
        int col = col0 + ctl * 16 + lc;          // C layout: col=lane&15
        float v = fmaxf(acc[rt][ctl][q], 0.f);
        int lin = (row * 1024 + col * 2) ^ ((row & 7) << 4);
        *(_Float16*)(O + lin) = (_Float16)v;
    }
}

// ---------------- fused MLP, fp16 MFMA, BM=32, 8 waves (32x64 per wave) ----------------
__launch_bounds__(MTHREADS, 4)
__global__ void mlp_mfma_kernel(const float* __restrict__ state,
                                const float* __restrict__ action,
                                const float* __restrict__ eps,
                                const float* __restrict__ b1,
                                const float* __restrict__ b2,
                                const float* __restrict__ b3,
                                const _Float16* __restrict__ w1,
                                const _Float16* __restrict__ w2,
                                const _Float16* __restrict__ w3,
                                const int* __restrict__ cnt, const int* __restrict__ bucket,
                                float* __restrict__ out) {
    __shared__ char smem[39936];
    char* xs = smem;                     // [32][112] fp16, stride 224B (7168 B)
    char* hs = smem + 7168;              // [32][512] fp16 swizzled (32768 B) — h1 then h2
    float* os = (float*)(smem + 7168);   // [32][132] fp32 (16896 B), overlays h after layer 3

    const int e    = blockIdx.x / TILES_PER_E;
    const int tile = blockIdx.x % TILES_PER_E;
    const int n    = cnt[e];
    const int m0   = tile * BM;
    if (m0 >= n) return;
    const int nrows = min(BM, n - m0);
    const int t = threadIdx.x;
    const int lane = t & 63;
    const int wv = t >> 6;
    const int col0 = wv * 64;            // 8 col-groups x 64 cols
    const int* brow = bucket + (size_t)e * B_ROWS;

    // ---- stage x = concat(state, action) fp16, 32x112 (cols>=80 zero) ----
    for (int i = t; i < BM * 112; i += MTHREADS) {
        int r = i / 112, c = i % 112;
        int rb = brow[min(m0 + r, n - 1)];
        float v = 0.f;
        if (c < STATE_DIM)      v = state[(size_t)rb * STATE_DIM + c];
        else if (c < IN_DIM)    v = action[(size_t)rb * ACTION_DIM + (c - STATE_DIM)];
        *(_Float16*)(xs + r * 224 + c * 2) = (_Float16)v;
    }
    __syncthreads();

    f32x4 acc[2][4];

    // ---- layer 1: h1 = relu(x @ W1 + b1), K=96, N=512 ----
    gemm_compute<224, false>(xs, 3,
        w1 + (size_t)e * L1_K8 * HIDDEN * 8,
        HIDDEN, b1 + (size_t)e * HIDDEN, acc, lane, col0);
    store_h(hs, acc, lane, col0);        // h region disjoint from x: no WAR hazard
    __syncthreads();

    // ---- layer 2: h2 = relu(h1 @ W2 + b2), K=512, N=512; h2 in regs until barrier ----
    gemm_compute<1024, true>(hs, 16,
        w2 + (size_t)e * L2_K8 * HIDDEN * 8,
        HIDDEN, b2 + (size_t)e * HIDDEN, acc, lane, col0);
    __syncthreads();                     // all h1 reads complete
    store_h(hs, acc, lane, col0);        // overwrite h1 with h2
    __syncthreads();

    // ---- layer 3: o = h2 @ W3 + b3, K=512, N=144; 18 units (rt=u&1, ct=u>>1) over 8 waves ----
    {
        const _Float16* Bw = w3 + (size_t)e * L3_K8 * L3_N * 8;
        const float* b3e = b3 + (size_t)e * OUT_DIM;
        const int lc = lane & 15, kg = lane >> 4;
        const int rt  = wv & 1;              // u=wv, wv+8, wv+16 all share rt
        const int ct0 = wv >> 1;             // 0..3
        const bool third = (wv < 2);         // u=wv+16 -> ct=8 (rt=0 for wv=0, rt=1 for wv=1)
        f32x4 o0 = {0.f,0.f,0.f,0.f}, o1 = o0, o2 = o0;
        const size_t bstep = (size_t)4 * L3_N * 8;
        const _Float16* bp0 = Bw + ((size_t)kg * L3_N + ct0 * 16 + lc) * 8;
        const _Float16* bp1 = Bw + ((size_t)kg * L3_N + (ct0 + 4) * 16 + lc) * 8;
        const _Float16* bp2 = Bw + ((size_t)kg * L3_N + 8 * 16 + lc) * 8;
        for (int ks = 0; ks < 16; ++ks) {
            int row = rt * 16 + lc;
            int lin = (row * 1024 + ks * 64 + kg * 16) ^ ((row & 7) << 4);
            half8 ah = *(const half8*)(hs + lin);
            half8 b0 = *(const half8*)(bp0 + (size_t)ks * bstep);
            half8 b1v = *(const half8*)(bp1 + (size_t)ks * bstep);
            o0 = __builtin_amdgcn_mfma_f32_16x16x32_f16(ah, b0, o0, 0, 0, 0);
            o1 = __builtin_amdgcn_mfma_f32_16x16x32_f16(ah, b1v, o1, 0, 0, 0);
            if (third) {
                half8 b2v = *(const half8*)(bp2 + (size_t)ks * bstep);
                o2 = __builtin_amdgcn_mfma_f32_16x16x32_f16(ah, b2v, o2, 0, 0, 0);
            }
        }
        __syncthreads();                 // all h2 reads complete (os overlays h)
        {
            int col = ct0 * 16 + lc;
            #pragma unroll
            for (int q = 0; q < 4; ++q) {
                int row = rt * 16 + kg * 4 + q;
                os[row * 132 + col] = o0[q] + b3e[col];
                if (col + 64 < OUT_DIM) os[row * 132 + col + 64] = o1[q] + b3e[col + 64];
            }
            if (third) {
                int col2 = 128 + lc;
                if (col2 < OUT_DIM) {
                    #pragma unroll
                    for (int q = 0; q < 4; ++q) {
                        int row = rt * 16 + kg * 4 + q;
                        os[row * 132 + col2] = o2[q] + b3e[col2];
                    }
                }
            }
        }
    }
    __syncthreads();

    // ---- epilogue ----
    for (int i = t; i < BM * D_OUT; i += MTHREADS) {
        int r = i / D_OUT, c = i % D_OUT;
        if (r >= nrows) continue;
        int rb = brow[m0 + r];
        float mu = os[r * 132 + c];
        float ls = fminf(fmaxf(os[r * 132 + c + D_OUT], -20.f), 2.f);
        float y  = fmaf(expf(ls), eps[(size_t)rb * D_OUT + c], mu);
        if (c < STATE_DIM) {
            out[(size_t)rb * STATE_DIM + c] = state[(size_t)rb * STATE_DIM + c] + y;
        } else {
            out[(size_t)B_ROWS * STATE_DIM + rb] = y;
        }
    }
}

// ================= fallback fp32 path (used if ws too small) =================
#define FB_BM      16
#define FB_THREADS 256
#define FB_TILES   ((B_ROWS + FB_BM - 1) / FB_BM)

__launch_bounds__(FB_THREADS, 2)
__global__ void mlp_fp32_kernel(const float* __restrict__ state,
                                const float* __restrict__ action,
                                const float* __restrict__ eps,
                                const float* __restrict__ W1, const float* __restrict__ b1,
                                const float* __restrict__ W2, const float* __restrict__ b2,
                                const float* __restrict__ W3, const float* __restrict__ b3,
                                const int* __restrict__ cnt, const int* __restrict__ bucket,
                                float* __restrict__ out) {
    __shared__ float xs[FB_BM][IN_DIM];
    __shared__ float h1[FB_BM][HIDDEN];
    __shared__ float h2[FB_BM][HIDDEN];
    __shared__ float os[FB_BM][OUT_DIM];
    __shared__ int   rows[FB_BM];

    const int e    = blockIdx.x / FB_TILES;
    const int tile = blockIdx.x % FB_TILES;
    const int n    = cnt[e];
    const int m0   = tile * FB_BM;
    if (m0 >= n) return;
    const int nrows = min(FB_BM, n - m0);
    const int t = threadIdx.x;

    if (t < FB_BM) rows[t] = (t < nrows) ? bucket[e * B_ROWS + m0 + t] : bucket[e * B_ROWS + m0];
    __syncthreads();

    for (int i = t; i < FB_BM * IN_DIM; i += FB_THREADS) {
        int r = i / IN_DIM, c = i % IN_DIM;
        int rb = rows[r];
        xs[r][c] = (c < STATE_DIM) ? state[(size_t)rb * STATE_DIM + c]
                                   : action[(size_t)rb * ACTION_DIM + (c - STATE_DIM)];
    }
    __syncthreads();

    const int c0 = 2 * t;
    {
        const float* We = W1 + (size_t)e * IN_DIM * HIDDEN;
        float acc0[FB_BM], acc1[FB_BM];
        const float bias0 = b1[(size_t)e * HIDDEN + c0];
        const float bias1 = b1[(size_t)e * HIDDEN + c0 + 1];
        #pragma unroll
        for (int r = 0; r < FB_BM; ++r) { acc0[r] = bias0; acc1[r] = bias1; }
        for (int k = 0; k < IN_DIM; k += 4) {
            float2 w0 = *(const float2*)&We[(size_t)(k + 0) * HIDDEN + c0];
            float2 w1v = *(const float2*)&We[(size_t)(k + 1) * HIDDEN + c0];
            float2 w2v = *(const float2*)&We[(size_t)(k + 2) * HIDDEN + c0];
            float2 w3v = *(const float2*)&We[(size_t)(k + 3) * HIDDEN + c0];
            #pragma unroll
            for (int r = 0; r < FB_BM; ++r) {
                float4 x = *(const float4*)&xs[r][k];
                acc0[r] = fmaf(x.x, w0.x, acc0[r]); acc1[r] = fmaf(x.x, w0.y, acc1[r]);
                acc0[r] = fmaf(x.y, w1v.x, acc0[r]); acc1[r] = fmaf(x.y, w1v.y, acc1[r]);
                acc0[r] = fmaf(x.z, w2v.x, acc0[r]); acc1[r] = fmaf(x.z, w2v.y, acc1[r]);
                acc0[r] = fmaf(x.w, w3v.x, acc0[r]); acc1[r] = fmaf(x.w, w3v.y, acc1[r]);
            }
        }
        #pragma unroll
        for (int r = 0; r < FB_BM; ++r)
            *(float2*)&h1[r][c0] = make_float2(fmaxf(acc0[r], 0.f), fmaxf(acc1[r], 0.f));
    }
    __syncthreads();
    {
        const float* We = W2 + (size_t)e * HIDDEN * HIDDEN;
        float acc0[FB_BM], acc1[FB_BM];
        const float bias0 = b2[(size_t)e * HIDDEN + c0];
        const float bias1 = b2[(size_t)e * HIDDEN + c0 + 1];
        #pragma unroll
        for (int r = 0; r < FB_BM; ++r) { acc0[r] = bias0; acc1[r] = bias1; }
        for (int k = 0; k < HIDDEN; k += 4) {
            float2 w0 = *(const float2*)&We[(size_t)(k + 0) * HIDDEN + c0];
            float2 w1v = *(const float2*)&We[(size_t)(k + 1) * HIDDEN + c0];
            float2 w2v = *(const float2*)&We[(size_t)(k + 2) * HIDDEN + c0];
            float2 w3v = *(const float2*)&We[(size_t)(k + 3) * HIDDEN + c0];
            #pragma unroll
            for (int r = 0; r < FB_BM; ++r) {
                float4 x = *(const float4*)&h1[r][k];
                acc0[r] = fmaf(x.x, w0.x, acc0[r]); acc1[r] = fmaf(x.x, w0.y, acc1[r]);
                acc0[r] = fmaf(x.y, w1v.x, acc0[r]); acc1[r] = fmaf(x.y, w1v.y, acc1[r]);
                acc0[r] = fmaf(x.z, w2v.x, acc0[r]); acc1[r] = fmaf(x.z, w2v.y, acc1[r]);
                acc0[r] = fmaf(x.w, w3v.x, acc0[r]); acc1[r] = fmaf(x.w, w3v.y, acc1[r]);
            }
        }
        #pragma unroll
        for (int r = 0; r < FB_BM; ++r)
            *(float2*)&h2[r][c0] = make_float2(fmaxf(acc0[r], 0.f), fmaxf(acc1[r], 0.f));
    }
    __syncthreads();
    {
        const float* We = W3 + (size_t)e * HIDDEN * OUT_DIM;
        for (int i = t; i < FB_BM * OUT_DIM; i += FB_THREADS) {
            int r = i / OUT_DIM, c = i % OUT_DIM;
            float acc = b3[(size_t)e * OUT_DIM + c];
            for (int k = 0; k < HIDDEN; k += 4) {
                float4 h = *(const float4*)&h2[r][k];
                acc = fmaf(h.x, We[(size_t)(k + 0) * OUT_DIM + c], acc);
                acc = fmaf(h.y, We[(size_t)(k + 1) * OUT_DIM + c], acc);
                acc = fmaf(h.z, We[(size_t)(k + 2) * OUT_DIM + c], acc);
                acc = fmaf(h.w, We[(size_t)(k + 3) * OUT_DIM + c], acc);
            }
            os[r][c] = acc;
        }
    }
    __syncthreads();
    for (int i = t; i < FB_BM * D_OUT; i += FB_THREADS) {
        int r = i / D_OUT, c = i % D_OUT;
        if (r >= nrows) continue;
        int rb = rows[r];
        float mu = os[r][c];
        float ls = fminf(fmaxf(os[r][c + D_OUT], -20.f), 2.f);
        float y  = fmaf(expf(ls), eps[(size_t)rb * D_OUT + c], mu);
        if (c < STATE_DIM) out[(size_t)rb * STATE_DIM + c] = state[(size_t)rb * STATE_DIM + c] + y;
        else               out[(size_t)B_ROWS * STATE_DIM + rb] = y;
    }
}

extern "C" void kernel_launch(void* const* d_in, const int* in_sizes, int n_in,
                              void* d_out, int out_size, void* d_ws, size_t ws_size,
                              hipStream_t stream) {
    const float* state  = (const float*)d_in[0];
    const float* action = (const float*)d_in[1];
    const float* eps    = (const float*)d_in[2];
    const float* W1     = (const float*)d_in[3];
    const float* b1     = (const float*)d_in[4];
    const float* W2     = (const float*)d_in[5];
    const float* b2     = (const float*)d_in[6];
    const float* W3     = (const float*)d_in[7];
    const float* b3     = (const float*)d_in[8];
    const int*   idx    = (const int*)d_in[9];
    float* out = (float*)d_out;

    int* cnt    = (int*)((char*)d_ws + OFF_CNT);
    int* bucket = (int*)((char*)d_ws + OFF_BUCKET);

    hipMemsetAsync(cnt, 0, ENSEMBLE * sizeof(int), stream);

    if (ws_size >= WS_NEEDED) {
        _Float16* w1 = (_Float16*)((char*)d_ws + OFF_W1);
        _Float16* w2 = (_Float16*)((char*)d_ws + OFF_W2);
        _Float16* w3 = (_Float16*)((char*)d_ws + OFF_W3);

        prep_kernel<<<BUCKET_BLOCKS + PACK_BLOCKS, 256, 0, stream>>>(
            idx, cnt, bucket, W1, W2, W3, w1, w2, w3);

        mlp_mfma_kernel<<<TOP_K * TILES_PER_E, MTHREADS, 0, stream>>>(
            state, action, eps, b1, b2, b3, w1, w2, w3, cnt, bucket, out);
    } else {
        prep_kernel<<<BUCKET_BLOCKS, 256, 0, stream>>>(
            idx, cnt, bucket, W1, W2, W3, (_Float16*)0, (_Float16*)0, (_Float16*)0);
        mlp_fp32_kernel<<<TOP_K * FB_TILES, FB_THREADS, 0, stream>>>(
            state, action, eps, W1, b1, W2, b2, W3, b3, cnt, bucket, out);
    }
}

// Round 8
// 114.270 us; speedup vs baseline: 6.9264x; 1.0807x over previous
//
#include <hip/hip_runtime.h>
#include <math.h>

#define B_ROWS     32768
#define STATE_DIM  64
#define ACTION_DIM 16
#define HIDDEN     512
#define ENSEMBLE   7
#define TOP_K      5
#define IN_DIM     80    // STATE_DIM + ACTION_DIM
#define OUT_DIM    130   // 2*(STATE_DIM+1)
#define D_OUT      65    // STATE_DIM+1

// ---- MFMA kernel geometry ----
#define BM         32
#define MTHREADS   512                           // 8 waves, each 32 rows x 64 cols
#define NTILES     (B_ROWS / BM + TOP_K)         // 1029 — exact-grid upper bound

// ---- packed weight dims ----
#define L1_K8 12      // K=96 (real 80)
#define L2_K8 64      // K=512
#define L3_K8 64      // K=512
#define L3_N  144     // N=130 padded to 9 col-tiles

#define N_W1 (TOP_K * L1_K8 * HIDDEN * 8)
#define N_W2 (TOP_K * L2_K8 * HIDDEN * 8)
#define N_W3 (TOP_K * L3_K8 * L3_N * 8)

#define OFF_CNT    0
#define OFF_BUCKET 256
#define OFF_W1     (OFF_BUCKET + ENSEMBLE * B_ROWS * 4)
#define OFF_W2     (OFF_W1 + N_W1 * 2)
#define OFF_W3     (OFF_W2 + N_W2 * 2)
#define WS_NEEDED  ((size_t)(OFF_W3 + N_W3 * 2))

// prep kernel: first blocks bucket, rest pack
#define BUCKET_BLOCKS ((B_ROWS + 255) / 256)                     // 128
#define PACK_G        (TOP_K * (L1_K8*HIDDEN + L2_K8*HIDDEN + L3_K8*L3_N))
#define PACK_BLOCKS   ((PACK_G + 255) / 256)

typedef __attribute__((ext_vector_type(8))) _Float16 half8;
typedef __attribute__((ext_vector_type(4))) float f32x4;

// ---------------- prep: bucket rows + pack weights (fused, one launch) ----------------
__global__ void prep_kernel(const int* __restrict__ idx,
                            int* __restrict__ cnt,
                            int* __restrict__ bucket,
                            const float* __restrict__ W1, const float* __restrict__ W2,
                            const float* __restrict__ W3,
                            _Float16* __restrict__ w1, _Float16* __restrict__ w2,
                            _Float16* __restrict__ w3) {
    if (blockIdx.x < BUCKET_BLOCKS) {
        int b = blockIdx.x * 256 + threadIdx.x;
        int lane = threadIdx.x & 63;
        int e = -1;
        if (b < B_ROWS) e = min(max(idx[b], 0), TOP_K - 1);
        #pragma unroll
        for (int ev = 0; ev < TOP_K; ++ev) {
            unsigned long long m = __ballot(e == ev);
            if (m == 0ull) continue;
            int leader = __ffsll((unsigned long long)m) - 1;
            int base = 0;
            if (lane == leader) base = atomicAdd(&cnt[ev], __popcll(m));
            base = __shfl(base, leader);
            if (e == ev) {
                int rank = __popcll(m & ((1ull << lane) - 1ull));
                bucket[ev * B_ROWS + base + rank] = b;
            }
        }
        return;
    }
    const int G1 = L1_K8 * HIDDEN;
    const int G2 = L2_K8 * HIDDEN;
    const int G3 = L3_K8 * L3_N;
    const int GPE = G1 + G2 + G3;
    int g = (blockIdx.x - BUCKET_BLOCKS) * 256 + threadIdx.x;
    if (g >= TOP_K * GPE) return;
    int e = g / GPE, r = g % GPE;

    const float* src; _Float16* dd;
    size_t dst; int k8, n, Kreal, Nreal, srcN;
    if (r < G1) {
        k8 = r / HIDDEN; n = r % HIDDEN;
        src = W1 + (size_t)e * IN_DIM * HIDDEN; Kreal = IN_DIM; Nreal = HIDDEN; srcN = HIDDEN;
        dd = w1; dst = (((size_t)e * L1_K8 + k8) * HIDDEN + n) * 8;
    } else if (r < G1 + G2) {
        int rr = r - G1; k8 = rr / HIDDEN; n = rr % HIDDEN;
        src = W2 + (size_t)e * HIDDEN * HIDDEN; Kreal = HIDDEN; Nreal = HIDDEN; srcN = HIDDEN;
        dd = w2; dst = (((size_t)e * L2_K8 + k8) * HIDDEN + n) * 8;
    } else {
        int rr = r - G1 - G2; k8 = rr / L3_N; n = rr % L3_N;
        src = W3 + (size_t)e * HIDDEN * OUT_DIM; Kreal = HIDDEN; Nreal = OUT_DIM; srcN = OUT_DIM;
        dd = w3; dst = (((size_t)e * L3_K8 + k8) * L3_N + n) * 8;
    }
    half8 hv;
    #pragma unroll
    for (int j = 0; j < 8; ++j) {
        int k = k8 * 8 + j;
        float v = (k < Kreal && n < Nreal) ? src[(size_t)k * srcN + n] : 0.f;
        hv[j] = (_Float16)v;
    }
    *(half8*)(dd + dst) = hv;
}

// ---------------- GEMM compute: 32 rows x 64 cols per wave ----------------
// Fully-unrolled K loop (compile-time KSTEPS), explicit 2-deep ping-pong B prefetch
// (all buffer indices compile-time constants so they live in registers).
template<int ASTR, bool SWZ, int KSTEPS>
__device__ __forceinline__ void gemm_compute(
    const char* A,
    const _Float16* __restrict__ B, int Bn, const float* __restrict__ bias,
    f32x4 (&acc)[2][4], int lane, int col0)
{
    const int lc = lane & 15, kg = lane >> 4;
    #pragma unroll
    for (int ctl = 0; ctl < 4; ++ctl) {
        float b = bias[col0 + ctl * 16 + lc];
        acc[0][ctl] = (f32x4){b, b, b, b};
        acc[1][ctl] = acc[0][ctl];
    }
    const size_t bstep = (size_t)4 * Bn * 8;   // elements per k-step (K advances 32)
    const _Float16* bp = B + ((size_t)kg * Bn + col0 + lc) * 8;

    half8 buf[2][4];
    #pragma unroll
    for (int ctl = 0; ctl < 4; ++ctl) buf[0][ctl] = *(const half8*)(bp + ctl * 128);

    #pragma unroll
    for (int ks = 0; ks < KSTEPS; ++ks) {
        const int cur = ks & 1, nxt = cur ^ 1;
        if (ks + 1 < KSTEPS) {
            const _Float16* pn = bp + (size_t)(ks + 1) * bstep;
            #pragma unroll
            for (int ctl = 0; ctl < 4; ++ctl) buf[nxt][ctl] = *(const half8*)(pn + ctl * 128);
        }
        half8 ah[2];
        #pragma unroll
        for (int rt = 0; rt < 2; ++rt) {
            int row = rt * 16 + lc;
            int lin = row * ASTR + ks * 64 + kg * 16;
            if (SWZ) lin ^= (row & 7) << 4;
            ah[rt] = *(const half8*)(A + lin);
        }
        #pragma unroll
        for (int rt = 0; rt < 2; ++rt)
        #pragma unroll
        for (int ctl = 0; ctl < 4; ++ctl)
            acc[rt][ctl] = __builtin_amdgcn_mfma_f32_16x16x32_f16(ah[rt], buf[cur][ctl], acc[rt][ctl], 0, 0, 0);
    }
}

// relu + fp16 + swizzled store into h region ([32][512] fp16, stride 1024B)
__device__ __forceinline__ void store_h(char* O, f32x4 (&acc)[2][4], int lane, int col0) {
    const int lc = lane & 15, kg = lane >> 4;
    #pragma unroll
    for (int rt = 0; rt < 2; ++rt)
    #pragma unroll
    for (int ctl = 0; ctl < 4; ++ctl)
    #pragma unroll
    for (int q = 0; q < 4; ++q) {
        int row = rt * 16 + kg * 4 + q;          // C layout: row=(lane>>4)*4+q
        int col = col0 + ctl * 16 + lc;          // C layout: col=lane&15
        float v = fmaxf(acc[rt][ctl][q], 0.f);
        int lin = (row * 1024 + col * 2) ^ ((row & 7) << 4);
        *(_Float16*)(O + lin) = (_Float16)v;
    }
}

// bijective XCD-chunk swizzle for NTILES workgroups on 8 XCDs (m204 variant)
__device__ __forceinline__ int xcd_swz(int orig) {
    const int nx = 8, q = NTILES / nx, r = NTILES % nx;
    int xcd = orig % nx, pos = orig / nx;
    int base = (xcd < r) ? xcd * (q + 1) : r * (q + 1) + (xcd - r) * q;
    return base + pos;
}

// ---------------- fused MLP, fp16 MFMA, BM=32, 8 waves (32x64 per wave) ----------------
__launch_bounds__(MTHREADS, 2)
__global__ void mlp_mfma_kernel(const float* __restrict__ state,
                                const float* __restrict__ action,
                                const float* __restrict__ eps,
                                const float* __restrict__ b1,
                                const float* __restrict__ b2,
                                const float* __restrict__ b3,
                                const _Float16* __restrict__ w1,
                                const _Float16* __restrict__ w2,
                                const _Float16* __restrict__ w3,
                                const int* __restrict__ cnt, const int* __restrict__ bucket,
                                float* __restrict__ out) {
    __shared__ char smem[39936];
    char* xs = smem;                     // [32][112] fp16, stride 224B (7168 B)
    char* hs = smem + 7168;              // [32][512] fp16 swizzled (32768 B) — h1 then h2
    float* os = (float*)(smem + 7168);   // [32][132] fp32 (16896 B), overlays h after layer 3

    // ---- exact-grid tile lookup: block j -> (e, tile), latched prefix scan ----
    const int j = xcd_swz(blockIdx.x);
    int e = TOP_K, base = 0;
    {
        int acct = 0;
        #pragma unroll
        for (int ev = 0; ev < TOP_K; ++ev) {
            int tiles = (cnt[ev] + BM - 1) / BM;
            if (e == TOP_K && j < acct + tiles) { e = ev; base = acct; }
            acct += tiles;
        }
    }
    if (e >= TOP_K) return;
    const int n    = cnt[e];
    const int tile = j - base;
    const int m0   = tile * BM;
    if (m0 >= n) return;
    const int nrows = min(BM, n - m0);
    const int t = threadIdx.x;
    const int lane = t & 63;
    const int wv = t >> 6;
    const int col0 = wv * 64;            // 8 col-groups x 64 cols
    const int* brow = bucket + (size_t)e * B_ROWS;

    // ---- stage x = concat(state, action) fp16, 32x112 (cols>=80 zero) ----
    for (int i = t; i < BM * 112; i += MTHREADS) {
        int r = i / 112, c = i % 112;
        int rb = brow[min(m0 + r, n - 1)];
        float v = 0.f;
        if (c < STATE_DIM)      v = state[(size_t)rb * STATE_DIM + c];
        else if (c < IN_DIM)    v = action[(size_t)rb * ACTION_DIM + (c - STATE_DIM)];
        *(_Float16*)(xs + r * 224 + c * 2) = (_Float16)v;
    }
    __syncthreads();

    f32x4 acc[2][4];

    // ---- layer 1: h1 = relu(x @ W1 + b1), K=96, N=512 ----
    gemm_compute<224, false, 3>(xs,
        w1 + (size_t)e * L1_K8 * HIDDEN * 8,
        HIDDEN, b1 + (size_t)e * HIDDEN, acc, lane, col0);
    store_h(hs, acc, lane, col0);        // h region disjoint from x: no WAR hazard
    __syncthreads();

    // ---- layer 2: h2 = relu(h1 @ W2 + b2), K=512, N=512; h2 in regs until barrier ----
    gemm_compute<1024, true, 16>(hs,
        w2 + (size_t)e * L2_K8 * HIDDEN * 8,
        HIDDEN, b2 + (size_t)e * HIDDEN, acc, lane, col0);
    __syncthreads();                     // all h1 reads complete
    store_h(hs, acc, lane, col0);        // overwrite h1 with h2
    __syncthreads();

    // ---- layer 3: o = h2 @ W3 + b3, K=512, N=144; ping-pong prefetched ----
    {
        const _Float16* Bw = w3 + (size_t)e * L3_K8 * L3_N * 8;
        const float* b3e = b3 + (size_t)e * OUT_DIM;
        const int lc = lane & 15, kg = lane >> 4;
        const int rt  = wv & 1;
        const int ct0 = wv >> 1;             // 0..3
        const bool third = (wv < 2);         // waves 0,1 also do ct=8
        f32x4 o0 = {0.f,0.f,0.f,0.f}, o1 = o0, o2 = o0;
        const size_t bstep = (size_t)4 * L3_N * 8;
        const _Float16* bp0 = Bw + ((size_t)kg * L3_N + ct0 * 16 + lc) * 8;
        const _Float16* bp1 = Bw + ((size_t)kg * L3_N + (ct0 + 4) * 16 + lc) * 8;
        const _Float16* bp2 = Bw + ((size_t)kg * L3_N + 8 * 16 + lc) * 8;

        half8 p0[2], p1[2], p2[2];
        p0[0] = *(const half8*)(bp0);
        p1[0] = *(const half8*)(bp1);
        if (third) p2[0] = *(const half8*)(bp2);

        #pragma unroll
        for (int ks = 0; ks < 16; ++ks) {
            const int cur = ks & 1, nxt = cur ^ 1;
            if (ks + 1 < 16) {
                p0[nxt] = *(const half8*)(bp0 + (size_t)(ks + 1) * bstep);
                p1[nxt] = *(const half8*)(bp1 + (size_t)(ks + 1) * bstep);
                if (third) p2[nxt] = *(const half8*)(bp2 + (size_t)(ks + 1) * bstep);
            }
            int row = rt * 16 + lc;
            int lin = (row * 1024 + ks * 64 + kg * 16) ^ ((row & 7) << 4);
            half8 ah = *(const half8*)(hs + lin);
            o0 = __builtin_amdgcn_mfma_f32_16x16x32_f16(ah, p0[cur], o0, 0, 0, 0);
            o1 = __builtin_amdgcn_mfma_f32_16x16x32_f16(ah, p1[cur], o1, 0, 0, 0);
            if (third) o2 = __builtin_amdgcn_mfma_f32_16x16x32_f16(ah, p2[cur], o2, 0, 0, 0);
        }
        __syncthreads();                 // all h2 reads complete (os overlays h)
        {
            int col = ct0 * 16 + lc;
            #pragma unroll
            for (int q = 0; q < 4; ++q) {
                int row = rt * 16 + kg * 4 + q;
                os[row * 132 + col] = o0[q] + b3e[col];
                if (col + 64 < OUT_DIM) os[row * 132 + col + 64] = o1[q] + b3e[col + 64];
            }
            if (third) {
                int col2 = 128 + lc;
                if (col2 < OUT_DIM) {
                    #pragma unroll
                    for (int q = 0; q < 4; ++q) {
                        int row = rt * 16 + kg * 4 + q;
                        os[row * 132 + col2] = o2[q] + b3e[col2];
                    }
                }
            }
        }
    }
    __syncthreads();

    // ---- epilogue ----
    for (int i = t; i < BM * D_OUT; i += MTHREADS) {
        int r = i / D_OUT, c = i % D_OUT;
        if (r >= nrows) continue;
        int rb = brow[m0 + r];
        float mu = os[r * 132 + c];
        float ls = fminf(fmaxf(os[r * 132 + c + D_OUT], -20.f), 2.f);
        float y  = fmaf(expf(ls), eps[(size_t)rb * D_OUT + c], mu);
        if (c < STATE_DIM) {
            out[(size_t)rb * STATE_DIM + c] = state[(size_t)rb * STATE_DIM + c] + y;
        } else {
            out[(size_t)B_ROWS * STATE_DIM + rb] = y;
        }
    }
}

// ================= fallback fp32 path (used if ws too small) =================
#define FB_BM      16
#define FB_THREADS 256
#define FB_TILES   ((B_ROWS + FB_BM - 1) / FB_BM)

__launch_bounds__(FB_THREADS, 2)
__global__ void mlp_fp32_kernel(const float* __restrict__ state,
                                const float* __restrict__ action,
                                const float* __restrict__ eps,
                                const float* __restrict__ W1, const float* __restrict__ b1,
                                const float* __restrict__ W2, const float* __restrict__ b2,
                                const float* __restrict__ W3, const float* __restrict__ b3,
                                const int* __restrict__ cnt, const int* __restrict__ bucket,
                                float* __restrict__ out) {
    __shared__ float xs[FB_BM][IN_DIM];
    __shared__ float h1[FB_BM][HIDDEN];
    __shared__ float h2[FB_BM][HIDDEN];
    __shared__ float os[FB_BM][OUT_DIM];
    __shared__ int   rows[FB_BM];

    const int e    = blockIdx.x / FB_TILES;
    const int tile = blockIdx.x % FB_TILES;
    const int n    = cnt[e];
    const int m0   = tile * FB_BM;
    if (m0 >= n) return;
    const int nrows = min(FB_BM, n - m0);
    const int t = threadIdx.x;

    if (t < FB_BM) rows[t] = (t < nrows) ? bucket[e * B_ROWS + m0 + t] : bucket[e * B_ROWS + m0];
    __syncthreads();

    for (int i = t; i < FB_BM * IN_DIM; i += FB_THREADS) {
        int r = i / IN_DIM, c = i % IN_DIM;
        int rb = rows[r];
        xs[r][c] = (c < STATE_DIM) ? state[(size_t)rb * STATE_DIM + c]
                                   : action[(size_t)rb * ACTION_DIM + (c - STATE_DIM)];
    }
    __syncthreads();

    const int c0 = 2 * t;
    {
        const float* We = W1 + (size_t)e * IN_DIM * HIDDEN;
        float acc0[FB_BM], acc1[FB_BM];
        const float bias0 = b1[(size_t)e * HIDDEN + c0];
        const float bias1 = b1[(size_t)e * HIDDEN + c0 + 1];
        #pragma unroll
        for (int r = 0; r < FB_BM; ++r) { acc0[r] = bias0; acc1[r] = bias1; }
        for (int k = 0; k < IN_DIM; k += 4) {
            float2 w0 = *(const float2*)&We[(size_t)(k + 0) * HIDDEN + c0];
            float2 w1v = *(const float2*)&We[(size_t)(k + 1) * HIDDEN + c0];
            float2 w2v = *(const float2*)&We[(size_t)(k + 2) * HIDDEN + c0];
            float2 w3v = *(const float2*)&We[(size_t)(k + 3) * HIDDEN + c0];
            #pragma unroll
            for (int r = 0; r < FB_BM; ++r) {
                float4 x = *(const float4*)&xs[r][k];
                acc0[r] = fmaf(x.x, w0.x, acc0[r]); acc1[r] = fmaf(x.x, w0.y, acc1[r]);
                acc0[r] = fmaf(x.y, w1v.x, acc0[r]); acc1[r] = fmaf(x.y, w1v.y, acc1[r]);
                acc0[r] = fmaf(x.z, w2v.x, acc0[r]); acc1[r] = fmaf(x.z, w2v.y, acc1[r]);
                acc0[r] = fmaf(x.w, w3v.x, acc0[r]); acc1[r] = fmaf(x.w, w3v.y, acc1[r]);
            }
        }
        #pragma unroll
        for (int r = 0; r < FB_BM; ++r)
            *(float2*)&h1[r][c0] = make_float2(fmaxf(acc0[r], 0.f), fmaxf(acc1[r], 0.f));
    }
    __syncthreads();
    {
        const float* We = W2 + (size_t)e * HIDDEN * HIDDEN;
        float acc0[FB_BM], acc1[FB_BM];
        const float bias0 = b2[(size_t)e * HIDDEN + c0];
        const float bias1 = b2[(size_t)e * HIDDEN + c0 + 1];
        #pragma unroll
        for (int r = 0; r < FB_BM; ++r) { acc0[r] = bias0; acc1[r] = bias1; }
        for (int k = 0; k < HIDDEN; k += 4) {
            float2 w0 = *(const float2*)&We[(size_t)(k + 0) * HIDDEN + c0];
            float2 w1v = *(const float2*)&We[(size_t)(k + 1) * HIDDEN + c0];
            float2 w2v = *(const float2*)&We[(size_t)(k + 2) * HIDDEN + c0];
            float2 w3v = *(const float2*)&We[(size_t)(k + 3) * HIDDEN + c0];
            #pragma unroll
            for (int r = 0; r < FB_BM; ++r) {
                float4 x = *(const float4*)&h1[r][k];
                acc0[r] = fmaf(x.x, w0.x, acc0[r]); acc1[r] = fmaf(x.x, w0.y, acc1[r]);
                acc0[r] = fmaf(x.y, w1v.x, acc0[r]); acc1[r] = fmaf(x.y, w1v.y, acc1[r]);
                acc0[r] = fmaf(x.z, w2v.x, acc0[r]); acc1[r] = fmaf(x.z, w2v.y, acc1[r]);
                acc0[r] = fmaf(x.w, w3v.x, acc0[r]); acc1[r] = fmaf(x.w, w3v.y, acc1[r]);
            }
        }
        #pragma unroll
        for (int r = 0; r < FB_BM; ++r)
            *(float2*)&h2[r][c0] = make_float2(fmaxf(acc0[r], 0.f), fmaxf(acc1[r], 0.f));
    }
    __syncthreads();
    {
        const float* We = W3 + (size_t)e * HIDDEN * OUT_DIM;
        for (int i = t; i < FB_BM * OUT_DIM; i += FB_THREADS) {
            int r = i / OUT_DIM, c = i % OUT_DIM;
            float acc = b3[(size_t)e * OUT_DIM + c];
            for (int k = 0; k < HIDDEN; k += 4) {
                float4 h = *(const float4*)&h2[r][k];
                acc = fmaf(h.x, We[(size_t)(k + 0) * OUT_DIM + c], acc);
                acc = fmaf(h.y, We[(size_t)(k + 1) * OUT_DIM + c], acc);
                acc = fmaf(h.z, We[(size_t)(k + 2) * OUT_DIM + c], acc);
                acc = fmaf(h.w, We[(size_t)(k + 3) * OUT_DIM + c], acc);
            }
            os[r][c] = acc;
        }
    }
    __syncthreads();
    for (int i = t; i < FB_BM * D_OUT; i += FB_THREADS) {
        int r = i / D_OUT, c = i % D_OUT;
        if (r >= nrows) continue;
        int rb = rows[r];
        float mu = os[r][c];
        float ls = fminf(fmaxf(os[r][c + D_OUT], -20.f), 2.f);
        float y  = fmaf(expf(ls), eps[(size_t)rb * D_OUT + c], mu);
        if (c < STATE_DIM) out[(size_t)rb * STATE_DIM + c] = state[(size_t)rb * STATE_DIM + c] + y;
        else               out[(size_t)B_ROWS * STATE_DIM + rb] = y;
    }
}

extern "C" void kernel_launch(void* const* d_in, const int* in_sizes, int n_in,
                              void* d_out, int out_size, void* d_ws, size_t ws_size,
                              hipStream_t stream) {
    const float* state  = (const float*)d_in[0];
    const float* action = (const float*)d_in[1];
    const float* eps    = (const float*)d_in[2];
    const float* W1     = (const float*)d_in[3];
    const float* b1     = (const float*)d_in[4];
    const float* W2     = (const float*)d_in[5];
    const float* b2     = (const float*)d_in[6];
    const float* W3     = (const float*)d_in[7];
    const float* b3     = (const float*)d_in[8];
    const int*   idx    = (const int*)d_in[9];
    float* out = (float*)d_out;

    int* cnt    = (int*)((char*)d_ws + OFF_CNT);
    int* bucket = (int*)((char*)d_ws + OFF_BUCKET);

    hipMemsetAsync(cnt, 0, ENSEMBLE * sizeof(int), stream);

    if (ws_size >= WS_NEEDED) {
        _Float16* w1 = (_Float16*)((char*)d_ws + OFF_W1);
        _Float16* w2 = (_Float16*)((char*)d_ws + OFF_W2);
        _Float16* w3 = (_Float16*)((char*)d_ws + OFF_W3);

        prep_kernel<<<BUCKET_BLOCKS + PACK_BLOCKS, 256, 0, stream>>>(
            idx, cnt, bucket, W1, W2, W3, w1, w2, w3);

        mlp_mfma_kernel<<<NTILES, MTHREADS, 0, stream>>>(
            state, action, eps, b1, b2, b3, w1, w2, w3, cnt, bucket, out);
    } else {
        prep_kernel<<<BUCKET_BLOCKS, 256, 0, stream>>>(
            idx, cnt, bucket, W1, W2, W3, (_Float16*)0, (_Float16*)0, (_Float16*)0);
        mlp_fp32_kernel<<<TOP_K * FB_TILES, FB_THREADS, 0, stream>>>(
            state, action, eps, W1, b1, W2, b2, W3, b3, cnt, bucket, out);
    }
}